// Round 3
// baseline (1873.921 us; speedup 1.0000x reference)
//
#include <hip/hip_runtime.h>
#include <stdint.h>

#define NA 50000          // atoms
#define DD 256            // embedding
#define NF 4              // formulas
#define NG 50000          // groundings (cliques) per formula
#define AA 3              // atoms per clique
#define MM (NG * AA)      // 150000 rows per formula
#define KK 512            // 2*D
#define BM 96             // divisible by 3 -> clique groups never split across tiles
#define BN 128
#define BK 32             // 4-deep ring
#define NSTEP (KK / BK)   // 16
#define MT ((MM + BM - 1) / BM)   // 1563

typedef __attribute__((ext_vector_type(8))) short s16x8;
typedef __attribute__((ext_vector_type(4))) float f32x4;

__device__ __forceinline__ unsigned short f2bf(float f) {
  union { float f; uint32_t u; } v; v.f = f;
  return (unsigned short)((v.u + 0x7FFFu + ((v.u >> 16) & 1u)) >> 16);  // RNE
}

__device__ __forceinline__ void gld_lds16(const void* g, void* l) {
  __builtin_amdgcn_global_load_lds(
      (const __attribute__((address_space(1))) uint32_t*)g,
      (__attribute__((address_space(3))) uint32_t*)l, 16, 0, 0);
}

// f32 -> bf16, 4 elems/thread
__global__ void cvt_f32_bf16(const float* __restrict__ src, unsigned short* __restrict__ dst, int n4) {
  int i = blockIdx.x * 256 + threadIdx.x;
  if (i < n4) {
    const float4 v = ((const float4*)src)[i];
    union { unsigned short s[4]; uint2 u; } o;
    o.s[0] = f2bf(v.x); o.s[1] = f2bf(v.y); o.s[2] = f2bf(v.z); o.s[3] = f2bf(v.w);
    ((uint2*)dst)[i] = o.u;
  }
}

// bf16 weights in BK=32 pre-chunked slot order: [f][nb][kb=0..15][s=0..511],
// slot s (8 bf16): c = s>>7 (k-chunk), nl = s&127; n = nb*128+nl; k = kb*32 + c*8 .. +7
__global__ void prep_w(const float* __restrict__ WM, const float* __restrict__ WU,
                       unsigned short* __restrict__ Wt0, unsigned short* __restrict__ Wt1) {
  const int slots0 = NF * 4 * 16 * 512;        // 131072
  const int slots1 = NF * 2 * 16 * 512;        // 65536
  int t = blockIdx.x * 256 + threadIdx.x;
  const float* src;
  int k;
  unsigned short* dst;
  if (t < slots0) {
    int f = t >> 15;
    int rem = t & 32767;
    int nb = rem >> 13, rem2 = rem & 8191;
    int kb = rem2 >> 9, s = rem2 & 511;
    int n = nb * 128 + (s & 127);
    k = kb * 32 + (s >> 7) * 8;
    if (n < 256) src = WM + ((size_t)f * 512) * 256 + n;
    else         src = WU + ((size_t)f * 512) * 256 + (n - 256);
    dst = Wt0 + (size_t)t * 8;
  } else if (t < slots0 + slots1) {
    int e = t - slots0;
    int f = e >> 14;
    int rem = e & 16383;
    int nb = rem >> 13, rem2 = rem & 8191;
    int kb = rem2 >> 9, s = rem2 & 511;
    int n = nb * 128 + (s & 127);
    k = kb * 32 + (s >> 7) * 8;
    src = WU + ((size_t)(NF + f) * 512) * 256 + n;
    dst = Wt1 + (size_t)e * 8;
  } else return;
  union { unsigned short h[8]; uint4 u; } o;
#pragma unroll
  for (int e2 = 0; e2 < 8; ++e2) o.h[e2] = f2bf(src[(size_t)(k + e2) * 256]);
  *(uint4*)dst = o.u;
}

// Fused gather-GEMM, 4-deep LDS ring + counted vmcnt (T3/T4).
// A row r: k<256 from atomSrc[gIdx[f,r]], k>=256 from gclSrc[f, r/3].
// LDS per ring buf, k-major chunks of 8 bf16: A slot = c*96+row, B slot = c*128+n.
template <int LAYER>
__global__ __launch_bounds__(256, 2)
void fgnn_gemm(const unsigned short* __restrict__ atomSrc,
               const unsigned short* __restrict__ gclSrc,
               const unsigned short* __restrict__ Wt,
               const int* __restrict__ gIdx,
               const float* __restrict__ bM,
               const float* __restrict__ bU,
               float* __restrict__ atomOut,          // f32 scatter-max target (u32 atomics)
               unsigned short* __restrict__ gclOut)  // bf16 [F*G][256] (layer 0, nt<2)
{
  constexpr int NOUT = (LAYER == 0) ? 512 : 256;
  constexpr int NB = NOUT / BN;
  const int mt = blockIdx.x, nt = blockIdx.y, f = blockIdx.z;
  const int m0 = mt * BM;
  const int tid = threadIdx.x;
  const int lane = tid & 63, wid = tid >> 6;
  const int wm = wid >> 1, wn = wid & 1;   // 2x2 wave grid: 48 rows x 64 cols per wave

  __shared__ union U {
    struct { unsigned short A[4][BM * BK]; unsigned short B[4][BN * BK]; } s;  // 24KB + 32KB
    float gc[BM * 130];                                                         // 48.8KB epilogue reuse
  } u;
  __shared__ int idx_lds[BM];

  if (tid < BM) {
    int r = m0 + tid; if (r > MM - 1) r = MM - 1;
    idx_lds[tid] = gIdx[(size_t)f * MM + r];
  }
  __syncthreads();

  // staging sources: 512B half-insts (lanes 0..31), 7 per wave per step (3 A + 4 B)
  // A piece j: chunk c = wid, rows j*32 + lane31 -> slot wid*96 + j*32 + lane31
  const unsigned short* pa[3];  // atom half (k < 256)
  const unsigned short* pg[3];  // gcl half  (k >= 256)
  const int l31 = lane & 31;
#pragma unroll
  for (int j = 0; j < 3; ++j) {
    int row = j * 32 + l31;
    int r = m0 + row; if (r > MM - 1) r = MM - 1;
    int idx = idx_lds[row];
    int g = r / 3;
    pa[j] = atomSrc + (size_t)idx * DD + wid * 8;
    pg[j] = gclSrc + ((size_t)f * NG + g) * DD + wid * 8;
  }
  // B piece j: slot (wid*4+j)*32 + lane31 (pre-chunked global: contiguous 512B)
  const unsigned short* pb[4];
  {
    const unsigned short* WtBlk = Wt + (size_t)(f * NB + nt) * (16 * 512 * 8);
#pragma unroll
    for (int j = 0; j < 4; ++j)
      pb[j] = WtBlk + (size_t)(((wid * 4 + j) * 32 + l31)) * 8;
  }

  auto stage = [&](int b, int ks) {
    if (lane < 32) {
#pragma unroll
      for (int j = 0; j < 3; ++j) {
        const unsigned short* src = (ks < 8) ? (pa[j] + ks * BK) : (pg[j] + (ks - 8) * BK);
        gld_lds16(src, &u.s.A[b][(wid * 3 + j) * 256]);
      }
#pragma unroll
      for (int j = 0; j < 4; ++j)
        gld_lds16(pb[j] + (size_t)ks * 4096, &u.s.B[b][(wid * 4 + j) * 256]);
    }
  };

  f32x4 acc[3][4];
#pragma unroll
  for (int m = 0; m < 3; ++m)
#pragma unroll
    for (int n = 0; n < 4; ++n) acc[m][n] = (f32x4)0.f;

  const int hi = lane >> 4, lo = lane & 15;

  // prologue: 3 buffers in flight (21 loads/wave)
  stage(0, 0); stage(1, 1); stage(2, 2);

#pragma unroll
  for (int ks = 0; ks < NSTEP; ++ks) {
    // wait for buffer ks (leave newer prefetches in flight), then sync
    if (ks <= NSTEP - 3)      asm volatile("s_waitcnt vmcnt(14)" ::: "memory");
    else if (ks == NSTEP - 2) asm volatile("s_waitcnt vmcnt(7)" ::: "memory");
    else                      asm volatile("s_waitcnt vmcnt(0)" ::: "memory");
    __builtin_amdgcn_sched_barrier(0);
    __builtin_amdgcn_s_barrier();
    __builtin_amdgcn_sched_barrier(0);
    if (ks + 3 < NSTEP) stage((ks + 3) & 3, ks + 3);

    const int b = ks & 3;
    s16x8 af[3], bf4[4];
#pragma unroll
    for (int m = 0; m < 3; ++m)
      af[m] = *(const s16x8*)&u.s.A[b][(hi * 96 + wm * 48 + m * 16 + lo) * 8];
#pragma unroll
    for (int n = 0; n < 4; ++n)
      bf4[n] = *(const s16x8*)&u.s.B[b][(hi * 128 + wn * 64 + n * 16 + lo) * 8];
    __builtin_amdgcn_s_setprio(1);
#pragma unroll
    for (int m = 0; m < 3; ++m)
#pragma unroll
      for (int n = 0; n < 4; ++n)
        acc[m][n] = __builtin_amdgcn_mfma_f32_16x16x32_bf16(af[m], bf4[n], acc[m][n], 0, 0, 0);
    __builtin_amdgcn_s_setprio(0);
  }

  // ---- epilogue ----
  if (LAYER == 0 && nt < 2) {
    // message path: relu(+b_M) -> max over the 3 rows of each clique -> gclOut (bf16)
    float bias_n[4];
#pragma unroll
    for (int n = 0; n < 4; ++n)
      bias_n[n] = bM[f * DD + nt * BN + wn * 64 + n * 16 + lo];
    __syncthreads();                                  // done with staging LDS
#pragma unroll
    for (int m = 0; m < 3; ++m)
#pragma unroll
      for (int n = 0; n < 4; ++n) {
        int col = wn * 64 + n * 16 + lo;
#pragma unroll
        for (int r = 0; r < 4; ++r) {
          int row = wm * 48 + m * 16 + (hi << 2) + r;  // C/D: col=lane&15, row=(lane>>4)*4+reg
          u.gc[row * 130 + col] = fmaxf(acc[m][n][r] + bias_n[n], 0.f);
        }
      }
    __syncthreads();
    int nvg = ((MM - m0 < BM) ? (MM - m0) : BM) / 3;
    for (int e = tid; e < 32 * BN; e += 256) {
      int grp = e >> 7, col = e & 127;
      if (grp < nvg) {
        float v = fmaxf(fmaxf(u.gc[(grp * 3 + 0) * 130 + col],
                              u.gc[(grp * 3 + 1) * 130 + col]),
                        u.gc[(grp * 3 + 2) * 130 + col]);
        gclOut[((size_t)f * NG + (size_t)(m0 / 3 + grp)) * DD + nt * BN + col] = f2bf(v);
      }
    }
  } else {
    // update path: relu(+b_U) -> scatter-max into atomOut via u32 atomicMax (values >= 0)
    const float* bp; int coloff;
    if (LAYER == 0) { bp = bU + f * DD;        coloff = (nt - 2) * BN; }
    else            { bp = bU + (NF + f) * DD; coloff = nt * BN; }
    float bias_n[4];
#pragma unroll
    for (int n = 0; n < 4; ++n)
      bias_n[n] = bp[coloff + wn * 64 + n * 16 + lo];
#pragma unroll
    for (int m = 0; m < 3; ++m)
#pragma unroll
      for (int r = 0; r < 4; ++r) {
        int rl = wm * 48 + m * 16 + (hi << 2) + r;
        if (m0 + rl < MM) {
          int idx = idx_lds[rl];
#pragma unroll
          for (int n = 0; n < 4; ++n) {
            int col = coloff + wn * 64 + n * 16 + lo;
            float v = fmaxf(acc[m][n][r] + bias_n[n], 0.f);
            atomicMax((unsigned int*)&atomOut[(size_t)idx * DD + col], __float_as_uint(v));
          }
        }
      }
  }
}

extern "C" void kernel_launch(void* const* d_in, const int* in_sizes, int n_in,
                              void* d_out, int out_size, void* d_ws, size_t ws_size,
                              hipStream_t stream) {
  const float* x  = (const float*)d_in[0];
  const int*   gi = (const int*)d_in[1];
  const float* fg = (const float*)d_in[2];
  const float* WM = (const float*)d_in[3];
  const float* bM = (const float*)d_in[4];
  const float* WU = (const float*)d_in[5];
  const float* bU = (const float*)d_in[6];
  float* out = (float*)d_out;

  char* ws = (char*)d_ws;
  size_t off = 0;
  auto alloc = [&](size_t b) { char* p = ws + off; off += (b + 255) & ~(size_t)255; return p; };
  unsigned short* gcl0  = (unsigned short*)alloc((size_t)NF * NG * DD * 2);   // 102.4 MB
  unsigned short* gcl1  = (unsigned short*)alloc((size_t)NF * NG * DD * 2);   // 102.4 MB
  unsigned short* atomB = (unsigned short*)alloc((size_t)NA * DD * 2);        // 25.6 MB
  unsigned short* Wt0   = (unsigned short*)alloc((size_t)NF * 512 * 512 * 2); // 2 MB
  unsigned short* Wt1   = (unsigned short*)alloc((size_t)NF * 256 * 512 * 2); // 1 MB

  // d_out doubles as the f32 layer-0 scatter target, then is re-zeroed for layer 1.
  hipMemsetAsync(d_out, 0, (size_t)NA * DD * 4, stream);

  cvt_f32_bf16<<<(NA * DD / 4 + 255) / 256, 256, 0, stream>>>(x, atomB, NA * DD / 4);
  cvt_f32_bf16<<<(NF * NG * DD / 4 + 255) / 256, 256, 0, stream>>>(fg, gcl0, NF * NG * DD / 4);
  prep_w<<<((NF * 4 * 16 * 512 + NF * 2 * 16 * 512) + 255) / 256, 256, 0, stream>>>(WM, WU, Wt0, Wt1);

  fgnn_gemm<0><<<dim3(MT, 4, NF), 256, 0, stream>>>(atomB, gcl0, Wt0, gi, bM, bU, out, gcl1);

  cvt_f32_bf16<<<(NA * DD / 4 + 255) / 256, 256, 0, stream>>>(out, atomB, NA * DD / 4);  // atom1 -> bf16
  hipMemsetAsync(d_out, 0, (size_t)NA * DD * 4, stream);

  fgnn_gemm<1><<<dim3(MT, 2, NF), 256, 0, stream>>>(atomB, gcl1, Wt1, gi, bM, bU, out, nullptr);
}

// Round 4
// 1781.681 us; speedup vs baseline: 1.0518x; 1.0518x over previous
//
#include <hip/hip_runtime.h>
#include <stdint.h>

#define NA 50000          // atoms
#define DD 256            // embedding
#define NF 4              // formulas
#define NG 50000          // groundings (cliques) per formula
#define AA 3              // atoms per clique
#define MM (NG * AA)      // 150000 rows per formula
#define TOT (NF * MM)     // 600000 total scatter rows
#define KK 512            // 2*D
#define BM 96             // divisible by 3 -> clique groups never split across tiles
#define BN 128
#define BK 64
#define MT ((MM + BM - 1) / BM)   // 1563

typedef __attribute__((ext_vector_type(8))) short s16x8;
typedef __attribute__((ext_vector_type(4))) float f32x4;

__device__ __forceinline__ unsigned short f2bf(float f) {
  union { float f; uint32_t u; } v; v.f = f;
  return (unsigned short)((v.u + 0x7FFFu + ((v.u >> 16) & 1u)) >> 16);  // RNE
}
__device__ __forceinline__ float bf2f(unsigned short h) {
  union { uint32_t u; float f; } v; v.u = ((uint32_t)h) << 16; return v.f;
}

__device__ __forceinline__ void gld_lds16(const void* g, void* l) {
  __builtin_amdgcn_global_load_lds(
      (const __attribute__((address_space(1))) uint32_t*)g,
      (__attribute__((address_space(3))) uint32_t*)l, 16, 0, 0);
}

// f32 -> bf16, 4 elems/thread
__global__ void cvt_f32_bf16(const float* __restrict__ src, unsigned short* __restrict__ dst, int n4) {
  int i = blockIdx.x * 256 + threadIdx.x;
  if (i < n4) {
    const float4 v = ((const float4*)src)[i];
    union { unsigned short s[4]; uint2 u; } o;
    o.s[0] = f2bf(v.x); o.s[1] = f2bf(v.y); o.s[2] = f2bf(v.z); o.s[3] = f2bf(v.w);
    ((uint2*)dst)[i] = o.u;
  }
}

// Transposed bf16 weights (R1 layout):
// Wt0[f][n][k], n in [0,512): n<256 -> W_M[0,f,k,n], else W_U[0,f,k,n-256]
// Wt1[f][n][k], n in [0,256): W_U[1,f,k,n]
__global__ void prep_w(const float* __restrict__ WM, const float* __restrict__ WU,
                       unsigned short* __restrict__ Wt0, unsigned short* __restrict__ Wt1) {
  const int total0 = NF * 512 * 512;
  const int total1 = NF * 256 * 512;
  int t = blockIdx.x * 256 + threadIdx.x;
  if (t < total0) {
    int f = t >> 18;
    int n = (t >> 9) & 511;
    int k = t & 511;
    float v = (n < 256) ? WM[(((size_t)f) * 512 + k) * 256 + n]
                        : WU[(((size_t)f) * 512 + k) * 256 + (n - 256)];
    Wt0[t] = f2bf(v);
  } else if (t < total0 + total1) {
    int e = t - total0;
    int f = e >> 17;
    int n = (e >> 9) & 255;
    int k = e & 511;
    float v = WU[(((size_t)(NF + f)) * 512 + k) * 256 + n];
    Wt1[e] = f2bf(v);
  }
}

// ---- counting-sort inversion of flat_idx (fixed per call, output-order-invariant) ----
__global__ void sort_count(const int* __restrict__ gi, uint32_t* __restrict__ cnt) {
  int t = blockIdx.x * 256 + threadIdx.x;
  if (t < TOT) atomicAdd(&cnt[gi[t]], 1u);
}

__global__ void sort_scan(const uint32_t* __restrict__ cnt, uint32_t* __restrict__ off,
                          uint32_t* __restrict__ bump) {
  __shared__ uint32_t part[1024];
  const int t = threadIdx.x;
  const int CH = 49;  // 1024*49 >= 50000
  int lo = t * CH, hi = lo + CH; if (hi > NA) hi = NA;
  uint32_t s = 0;
  for (int i = lo; i < hi; ++i) s += cnt[i];
  part[t] = s;
  __syncthreads();
  for (int d = 1; d < 1024; d <<= 1) {
    uint32_t v = (t >= d) ? part[t - d] : 0u;
    __syncthreads();
    part[t] += v;
    __syncthreads();
  }
  uint32_t run = (t == 0) ? 0u : part[t - 1];
  for (int i = lo; i < hi; ++i) { off[i] = run; bump[i] = run; run += cnt[i]; }
  if (t == 1023) off[NA] = part[1023];
}

__global__ void sort_fill(const int* __restrict__ gi, uint32_t* __restrict__ bump,
                          uint32_t* __restrict__ rank) {
  int t = blockIdx.x * 256 + threadIdx.x;
  if (t < TOT) rank[t] = atomicAdd(&bump[gi[t]], 1u);
}

// Streaming per-atom run max over fiBuf (bf16, non-negative -> u16 compare == bf16 compare).
template <int LAYER>
__global__ __launch_bounds__(256)
void reduce_max(const unsigned short* __restrict__ fiBuf, const uint32_t* __restrict__ off,
                unsigned short* __restrict__ outB, float* __restrict__ outF, int c0) {
  const int wid = threadIdx.x >> 6, lane = threadIdx.x & 63;
  const int a = blockIdx.x * 4 + wid;
  if (a >= NA) return;
  uint32_t s = off[a], e = off[a + 1];
  unsigned short mx0 = 0, mx1 = 0;
  for (uint32_t j = s; j < e; ++j) {
    uint32_t v = *(const uint32_t*)&fiBuf[(size_t)j * 128 + lane * 2];
    unsigned short v0 = (unsigned short)(v & 0xffffu), v1 = (unsigned short)(v >> 16);
    if (v0 > mx0) mx0 = v0;
    if (v1 > mx1) mx1 = v1;
  }
  if (LAYER == 0) {
    *(uint32_t*)&outB[(size_t)a * DD + c0 + lane * 2] = (uint32_t)mx0 | ((uint32_t)mx1 << 16);
  } else {
    float2 o; o.x = bf2f(mx0); o.y = bf2f(mx1);
    *(float2*)&outF[(size_t)a * DD + c0 + lane * 2] = o;
  }
}

// Fused gather-GEMM (R1 core). Per-layer epilogues:
//  msg (L0): relu(+b_M) -> clique max -> gclOut
//  upd SORT: relu(+b_U) -> LDS transpose -> plain 16B stores to fiBuf[rank[row]]
//  upd !SORT: relu(+b_U) -> atomicMax scatter (fallback)
template <int LAYER, bool SORT>
__global__ __launch_bounds__(256, 2)
void fgnn_gemm(const unsigned short* __restrict__ atomSrc,
               const unsigned short* __restrict__ gclSrc,
               const unsigned short* __restrict__ Wt,
               const int* __restrict__ gIdx,
               const float* __restrict__ bM,
               const float* __restrict__ bU,
               float* __restrict__ atomOut,
               unsigned short* __restrict__ gclOut,
               unsigned short* __restrict__ fiBuf,
               const uint32_t* __restrict__ rank,
               int half)
{
  constexpr int NOUT = (LAYER == 0) ? 512 : 256;
  constexpr int MSGC = SORT ? (LAYER == 0 ? 1 : 0) : (LAYER == 0 ? 2 : 0);
  const int mt = blockIdx.x, y = blockIdx.y, f = blockIdx.z;
  const bool isMsg = (MSGC > 0) && (y < MSGC);
  const int n0 = SORT ? (half * BN + ((LAYER == 0 && !isMsg) ? 256 : 0)) : y * BN;
  const int m0 = mt * BM;
  const int tid = threadIdx.x;
  const int lane = tid & 63, wid = tid >> 6;
  const int wm = wid >> 1, wn = wid & 1;   // 2x2 wave grid: 48 rows x 64 cols

  __shared__ union U {
    struct { unsigned short A[2][BM * BK]; unsigned short B[2][BN * BK]; } s;  // 56KB
    float gc[BM * 130];                                                         // 49.9KB
  } u;
  __shared__ int idx_lds[BM];
  __shared__ uint32_t rank_lds[BM];

  if (tid < BM) {
    int r = m0 + tid; if (r > MM - 1) r = MM - 1;
    idx_lds[tid] = gIdx[(size_t)f * MM + r];
    if (SORT) rank_lds[tid] = rank[(size_t)f * MM + r];
  }
  __syncthreads();

  // staging source pointers (XOR chunk swizzle on GLOBAL side; LDS dest linear)
  const unsigned short* paA[3];
  const unsigned short* paG[3];
#pragma unroll
  for (int i = 0; i < 3; ++i) {
    int row = wid * 8 + i * 32 + (lane >> 3);       // 0..95
    int c = (lane & 7) ^ (row & 7);
    int r = m0 + row; if (r > MM - 1) r = MM - 1;
    int idx = idx_lds[row];
    int g = r / 3;
    paA[i] = atomSrc + (size_t)idx * DD + c * 8;
    paG[i] = gclSrc + ((size_t)f * NG + g) * DD + c * 8;
  }
  const unsigned short* pB[4];
#pragma unroll
  for (int i = 0; i < 4; ++i) {
    int nrow = wid * 8 + i * 32 + (lane >> 3);      // 0..127
    int c = (lane & 7) ^ (nrow & 7);
    pB[i] = Wt + ((size_t)f * NOUT + n0 + nrow) * KK + c * 8;
  }

  auto stage = [&](int buf, int k0) {
#pragma unroll
    for (int i = 0; i < 3; ++i) {
      const unsigned short* src = (k0 < DD) ? (paA[i] + k0) : (paG[i] + (k0 - DD));
      gld_lds16(src, &u.s.A[buf][i * 2048 + wid * 512]);
    }
#pragma unroll
    for (int i = 0; i < 4; ++i)
      gld_lds16(pB[i] + k0, &u.s.B[buf][i * 2048 + wid * 512]);
  };

  f32x4 acc[3][4];
#pragma unroll
  for (int m = 0; m < 3; ++m)
#pragma unroll
    for (int n = 0; n < 4; ++n) acc[m][n] = (f32x4)0.f;

  stage(0, 0);
  int cur = 0;
  const int hi = lane >> 4, lo = lane & 15;
  for (int ks = 0; ks < KK / BK; ++ks) {
    __syncthreads();
    if (ks + 1 < KK / BK) stage(cur ^ 1, (ks + 1) * BK);
#pragma unroll
    for (int kk = 0; kk < 2; ++kk) {
      s16x8 af[3], bf4[4];
#pragma unroll
      for (int m = 0; m < 3; ++m) {
        int row = wm * 48 + m * 16 + lo;
        int c = kk * 4 + hi;
        af[m] = *(const s16x8*)&u.s.A[cur][row * BK + ((c ^ (row & 7)) << 3)];
      }
#pragma unroll
      for (int n = 0; n < 4; ++n) {
        int nr = wn * 64 + n * 16 + lo;
        int c = kk * 4 + hi;
        bf4[n] = *(const s16x8*)&u.s.B[cur][nr * BK + ((c ^ (nr & 7)) << 3)];
      }
#pragma unroll
      for (int m = 0; m < 3; ++m)
#pragma unroll
        for (int n = 0; n < 4; ++n)
          acc[m][n] = __builtin_amdgcn_mfma_f32_16x16x32_bf16(af[m], bf4[n], acc[m][n], 0, 0, 0);
    }
    cur ^= 1;
  }

  // ---- epilogues ----
  if (LAYER == 0 && isMsg) {
    float bias_n[4];
#pragma unroll
    for (int n = 0; n < 4; ++n)
      bias_n[n] = bM[f * DD + n0 + wn * 64 + n * 16 + lo];
    __syncthreads();
#pragma unroll
    for (int m = 0; m < 3; ++m)
#pragma unroll
      for (int n = 0; n < 4; ++n) {
        int col = wn * 64 + n * 16 + lo;
#pragma unroll
        for (int r = 0; r < 4; ++r) {
          int row = wm * 48 + m * 16 + (hi << 2) + r;  // C/D: col=lane&15, row=(lane>>4)*4+reg
          u.gc[row * 130 + col] = fmaxf(acc[m][n][r] + bias_n[n], 0.f);
        }
      }
    __syncthreads();
    int nvg = ((MM - m0 < BM) ? (MM - m0) : BM) / 3;
    for (int e = tid; e < 32 * BN; e += 256) {
      int grp = e >> 7, col = e & 127;
      if (grp < nvg) {
        float v = fmaxf(fmaxf(u.gc[(grp * 3 + 0) * 130 + col],
                              u.gc[(grp * 3 + 1) * 130 + col]),
                        u.gc[(grp * 3 + 2) * 130 + col]);
        gclOut[((size_t)f * NG + (size_t)(m0 / 3 + grp)) * DD + n0 + col] = f2bf(v);
      }
    }
  } else if (SORT) {
    // update path, sorted materialization: relu -> LDS -> 16B stores to fiBuf[rank]
    const int ocol0 = half * BN;
    const float* bp = bU + (size_t)((LAYER ? NF : 0) + f) * DD + ocol0;
    float bias_n[4];
#pragma unroll
    for (int n = 0; n < 4; ++n)
      bias_n[n] = bp[wn * 64 + n * 16 + lo];
    __syncthreads();
#pragma unroll
    for (int m = 0; m < 3; ++m)
#pragma unroll
      for (int n = 0; n < 4; ++n) {
        int col = wn * 64 + n * 16 + lo;
#pragma unroll
        for (int r = 0; r < 4; ++r) {
          int row = wm * 48 + m * 16 + (hi << 2) + r;
          u.gc[row * 130 + col] = fmaxf(acc[m][n][r] + bias_n[n], 0.f);
        }
      }
    __syncthreads();
    for (int e = tid; e < BM * 16; e += 256) {   // 16 x 16B parts per 128-col row
      int row = e >> 4, part = e & 15;
      if (m0 + row < MM) {
        uint32_t rk = rank_lds[row];
        union { unsigned short h[8]; uint4 u4; } o;
#pragma unroll
        for (int j = 0; j < 8; ++j) o.h[j] = f2bf(u.gc[row * 130 + part * 8 + j]);
        *(uint4*)&fiBuf[(size_t)rk * 128 + part * 8] = o.u4;
      }
    }
  } else {
    // update path, atomic fallback
    const int ocol0 = n0 - (LAYER == 0 ? 256 : 0);
    const float* bp = bU + (size_t)((LAYER ? NF : 0) + f) * DD;
    float bias_n[4];
#pragma unroll
    for (int n = 0; n < 4; ++n)
      bias_n[n] = bp[ocol0 + wn * 64 + n * 16 + lo];
#pragma unroll
    for (int m = 0; m < 3; ++m)
#pragma unroll
      for (int r = 0; r < 4; ++r) {
        int rl = wm * 48 + m * 16 + (hi << 2) + r;
        if (m0 + rl < MM) {
          int idx = idx_lds[rl];
#pragma unroll
          for (int n = 0; n < 4; ++n) {
            int col = ocol0 + wn * 64 + n * 16 + lo;
            float v = fmaxf(acc[m][n][r] + bias_n[n], 0.f);
            atomicMax((unsigned int*)&atomOut[(size_t)idx * DD + col], __float_as_uint(v));
          }
        }
      }
  }
}

extern "C" void kernel_launch(void* const* d_in, const int* in_sizes, int n_in,
                              void* d_out, int out_size, void* d_ws, size_t ws_size,
                              hipStream_t stream) {
  const float* x  = (const float*)d_in[0];
  const int*   gi = (const int*)d_in[1];
  const float* fg = (const float*)d_in[2];
  const float* WM = (const float*)d_in[3];
  const float* bM = (const float*)d_in[4];
  const float* WU = (const float*)d_in[5];
  const float* bU = (const float*)d_in[6];
  float* out = (float*)d_out;

  char* ws = (char*)d_ws;
  size_t off_b = 0;
  auto alloc = [&](size_t b) { char* p = ws + off_b; off_b += (b + 255) & ~(size_t)255; return p; };
  unsigned short* gcl0   = (unsigned short*)alloc((size_t)NF * NG * DD * 2);   // 102.4 MB
  unsigned short* gcl1   = (unsigned short*)alloc((size_t)NF * NG * DD * 2);   // 102.4 MB
  unsigned short* atomB  = (unsigned short*)alloc((size_t)NA * DD * 2);        // 25.6 MB
  unsigned short* Wt0    = (unsigned short*)alloc((size_t)NF * 512 * 512 * 2); // 2 MB
  unsigned short* Wt1    = (unsigned short*)alloc((size_t)NF * 256 * 512 * 2); // 1 MB
  size_t base_need = off_b;
  unsigned short* atomB2 = (unsigned short*)alloc((size_t)NA * DD * 2);        // 25.6 MB
  uint32_t* cnt   = (uint32_t*)alloc((size_t)NA * 4);
  uint32_t* offA  = (uint32_t*)alloc((size_t)(NA + 1) * 4);
  uint32_t* bump  = (uint32_t*)alloc((size_t)NA * 4);
  uint32_t* rank  = (uint32_t*)alloc((size_t)TOT * 4);                          // 2.4 MB
  unsigned short* fiBuf = (unsigned short*)alloc((size_t)TOT * 128 * 2);        // 153.6 MB
  const bool useSort = ws_size >= off_b;
  (void)base_need;

  cvt_f32_bf16<<<(NA * DD / 4 + 255) / 256, 256, 0, stream>>>(x, atomB, NA * DD / 4);
  cvt_f32_bf16<<<(NF * NG * DD / 4 + 255) / 256, 256, 0, stream>>>(fg, gcl0, NF * NG * DD / 4);
  prep_w<<<((NF * 512 * 512 + NF * 256 * 512) + 255) / 256, 256, 0, stream>>>(WM, WU, Wt0, Wt1);

  if (useSort) {
    hipMemsetAsync(cnt, 0, (size_t)NA * 4, stream);
    sort_count<<<(TOT + 255) / 256, 256, 0, stream>>>(gi, cnt);
    sort_scan<<<1, 1024, 0, stream>>>(cnt, offA, bump);
    sort_fill<<<(TOT + 255) / 256, 256, 0, stream>>>(gi, bump, rank);

    for (int h = 0; h < 2; ++h) {
      fgnn_gemm<0, true><<<dim3(MT, 2, NF), 256, 0, stream>>>(
          atomB, gcl0, Wt0, gi, bM, bU, nullptr, gcl1, fiBuf, rank, h);
      reduce_max<0><<<(NA + 3) / 4, 256, 0, stream>>>(fiBuf, offA, atomB2, nullptr, h * BN);
    }
    for (int h = 0; h < 2; ++h) {
      fgnn_gemm<1, true><<<dim3(MT, 1, NF), 256, 0, stream>>>(
          atomB2, gcl1, Wt1, gi, bM, bU, nullptr, nullptr, fiBuf, rank, h);
      reduce_max<1><<<(NA + 3) / 4, 256, 0, stream>>>(fiBuf, offA, nullptr, out, h * BN);
    }
  } else {
    // atomic fallback (R1 path)
    hipMemsetAsync(d_out, 0, (size_t)NA * DD * 4, stream);
    fgnn_gemm<0, false><<<dim3(MT, 4, NF), 256, 0, stream>>>(
        atomB, gcl0, Wt0, gi, bM, bU, out, gcl1, nullptr, nullptr, 0);
    cvt_f32_bf16<<<(NA * DD / 4 + 255) / 256, 256, 0, stream>>>(out, atomB, NA * DD / 4);
    hipMemsetAsync(d_out, 0, (size_t)NA * DD * 4, stream);
    fgnn_gemm<1, false><<<dim3(MT, 2, NF), 256, 0, stream>>>(
        atomB, gcl1, Wt1, gi, bM, bU, out, nullptr, nullptr, nullptr, 0);
  }
}

// Round 5
// 1384.249 us; speedup vs baseline: 1.3537x; 1.2871x over previous
//
#include <hip/hip_runtime.h>
#include <stdint.h>

#define NA 50000          // atoms
#define DD 256            // embedding
#define NF 4              // formulas
#define NG 50000          // cliques per formula
#define MM 150000         // rows per formula (NG*3)
#define TOT 600000        // NF*MM scatter rows
#define KK 512            // 2*D
#define BM 96             // divisible by 3: clique groups never split
#define BK 32
#define NO 256            // output cols per dispatch
#define NSTEP (KK / BK)   // 16
#define MT ((MM + BM - 1) / BM)   // 1563

typedef __attribute__((ext_vector_type(8))) short s16x8;
typedef __attribute__((ext_vector_type(4))) float f32x4;

__device__ __forceinline__ unsigned short f2bf(float f) {
  union { float f; uint32_t u; } v; v.f = f;
  return (unsigned short)((v.u + 0x7FFFu + ((v.u >> 16) & 1u)) >> 16);  // RNE
}
__device__ __forceinline__ float bf2f(unsigned short h) {
  union { uint32_t u; float f; } v; v.u = ((uint32_t)h) << 16; return v.f;
}
__device__ __forceinline__ void gld_lds16(const void* g, void* l) {
  __builtin_amdgcn_global_load_lds(
      (const __attribute__((address_space(1))) uint32_t*)g,
      (__attribute__((address_space(3))) uint32_t*)l, 16, 0, 0);
}

__global__ void cvt_f32_bf16(const float* __restrict__ src, unsigned short* __restrict__ dst, int n4) {
  int i = blockIdx.x * 256 + threadIdx.x;
  if (i < n4) {
    const float4 v = ((const float4*)src)[i];
    union { unsigned short s[4]; uint2 u; } o;
    o.s[0] = f2bf(v.x); o.s[1] = f2bf(v.y); o.s[2] = f2bf(v.z); o.s[3] = f2bf(v.w);
    ((uint2*)dst)[i] = o.u;
  }
}

// Three 256-col weight matrices, pre-chunked for BK=32 staging:
// Wt[w][f][kb=0..15][c=0..3][n=0..255], each slot = 8 bf16 (k = kb*32 + c*8 + e).
// w: 0 = W_M[0], 1 = W_U[0], 2 = W_U[1]
__global__ void prep_w(const float* __restrict__ WM, const float* __restrict__ WU,
                       unsigned short* __restrict__ Wt) {
  const int per = NF * 16384;                  // slots per matrix
  int t = blockIdx.x * 256 + threadIdx.x;
  if (t >= 3 * per) return;
  int w = t / per, r = t % per;
  int f = r >> 14;
  int kb = (r >> 10) & 15;
  int c  = (r >> 8) & 3;
  int n  = r & 255;
  int k = kb * 32 + c * 8;
  const float* src = (w == 0) ? WM + ((size_t)f * 512 + k) * 256 + n
                   : (w == 1) ? WU + ((size_t)f * 512 + k) * 256 + n
                              : WU + ((size_t)(NF + f) * 512 + k) * 256 + n;
  union { unsigned short h[8]; uint4 u; } o;
#pragma unroll
  for (int e = 0; e < 8; ++e) o.h[e] = f2bf(src[(size_t)e * 256]);
  ((uint4*)Wt)[t] = o.u;
}

// ---- counting-sort inversion of flat_idx (fixed input; output order-invariant) ----
__global__ void sort_count(const int* __restrict__ gi, uint32_t* __restrict__ cnt) {
  int t = blockIdx.x * 256 + threadIdx.x;
  if (t < TOT) atomicAdd(&cnt[gi[t]], 1u);
}
__global__ void sort_scan(const uint32_t* __restrict__ cnt, uint32_t* __restrict__ off,
                          uint32_t* __restrict__ bump) {
  __shared__ uint32_t part[1024];
  const int t = threadIdx.x;
  const int CH = 49;
  int lo = t * CH, hi = lo + CH; if (hi > NA) hi = NA;
  uint32_t s = 0;
  for (int i = lo; i < hi; ++i) s += cnt[i];
  part[t] = s;
  __syncthreads();
  for (int d = 1; d < 1024; d <<= 1) {
    uint32_t v = (t >= d) ? part[t - d] : 0u;
    __syncthreads();
    part[t] += v;
    __syncthreads();
  }
  uint32_t run = (t == 0) ? 0u : part[t - 1];
  for (int i = lo; i < hi; ++i) { off[i] = run; bump[i] = run; run += cnt[i]; }
  if (t == 1023) off[NA] = part[1023];
}
__global__ void sort_fill(const int* __restrict__ gi, uint32_t* __restrict__ bump,
                          uint32_t* __restrict__ rank) {
  int t = blockIdx.x * 256 + threadIdx.x;
  if (t < TOT) rank[t] = atomicAdd(&bump[gi[t]], 1u);
}

// Per-atom run max over 256-wide fiBuf rows (bf16 >= 0 -> u16 order == float order).
template <int LAYER>
__global__ __launch_bounds__(256)
void reduce_max(const unsigned short* __restrict__ fiBuf, const uint32_t* __restrict__ off,
                unsigned short* __restrict__ outB, float* __restrict__ outF) {
  const int wid = threadIdx.x >> 6, lane = threadIdx.x & 63;
  const int a = blockIdx.x * 4 + wid;
  if (a >= NA) return;
  uint32_t s = off[a], e = off[a + 1];
  unsigned short mx[4] = {0, 0, 0, 0};
  for (uint32_t j = s; j < e; ++j) {
    uint2 v = *(const uint2*)&fiBuf[(size_t)j * NO + lane * 4];
    unsigned short a0 = (unsigned short)(v.x & 0xffffu), a1 = (unsigned short)(v.x >> 16);
    unsigned short a2 = (unsigned short)(v.y & 0xffffu), a3 = (unsigned short)(v.y >> 16);
    if (a0 > mx[0]) mx[0] = a0;
    if (a1 > mx[1]) mx[1] = a1;
    if (a2 > mx[2]) mx[2] = a2;
    if (a3 > mx[3]) mx[3] = a3;
  }
  if (LAYER == 0) {
    uint2 o; o.x = (uint32_t)mx[0] | ((uint32_t)mx[1] << 16);
    o.y = (uint32_t)mx[2] | ((uint32_t)mx[3] << 16);
    *(uint2*)&outB[(size_t)a * DD + lane * 4] = o;
  } else {
    float4 o; o.x = bf2f(mx[0]); o.y = bf2f(mx[1]); o.z = bf2f(mx[2]); o.w = bf2f(mx[3]);
    *(float4*)&outF[(size_t)a * DD + lane * 4] = o;
  }
}

// N-fused gather-GEMM: 96 rows x 256 cols per block, BK=32, 1x4 wave grid
// (wave w owns rows 0..95 x cols w*64..w*64+63; acc 6x4 frags).
// A row r: k<256 from atomSrc[gIdx[f,r]], k>=256 from gclSrc[f, r/3].
// EPI: 0 = msg (clique-max -> gclOut), 1 = upd sorted (fiBuf[rank]), 2 = upd atomicMax.
template <int EPI>
__global__ __launch_bounds__(256, 3)
void fgnn_gemm(const unsigned short* __restrict__ atomSrc,
               const unsigned short* __restrict__ gclSrc,
               const unsigned short* __restrict__ Wt,   // prechunked [f][16][4][256]*8
               const int* __restrict__ gIdx,
               const float* __restrict__ bias,          // + f*DD + col
               float* __restrict__ atomOut,
               unsigned short* __restrict__ gclOut,
               unsigned short* __restrict__ fiBuf,
               const uint32_t* __restrict__ rank)
{
  const int mt = blockIdx.x, f = blockIdx.y;
  const int m0 = mt * BM;
  const int tid = threadIdx.x;
  const int lane = tid & 63, wid = tid >> 6;
  const int hi = lane >> 4, lo = lane & 15;

  __shared__ union U {
    struct { unsigned short A[2][384 * 8]; unsigned short B[2][1024 * 8]; } s;  // 12KB + 32KB
    float gc[BM * 130];                                                          // 49.9KB
  } u;
  __shared__ int idx_lds[BM];
  __shared__ uint32_t rank_lds[BM];

  if (tid < BM) {
    int r = m0 + tid; if (r > MM - 1) r = MM - 1;
    idx_lds[tid] = gIdx[(size_t)f * MM + r];
    if (EPI == 1) rank_lds[tid] = rank[(size_t)f * MM + r];
  }
  __syncthreads();

  // A staging sources: 6 wave-insts/step cover slots s = q*64+lane, slot = c*96+row.
  // waves 0,1 issue q = wid, wid+4; waves 2,3 issue q = wid.
  const unsigned short* pa[2];
  const unsigned short* pg[2];
#pragma unroll
  for (int j = 0; j < 2; ++j) {
    int q = j * 4 + wid;
    if (q < 6) {
      int s = q * 64 + lane;
      int c = (s * 1366) >> 17;           // s / 96  (valid s < 384)
      int row = s - c * 96;
      int r = m0 + row; if (r > MM - 1) r = MM - 1;
      int idx = idx_lds[row];
      int g = r / 3;
      pa[j] = atomSrc + (size_t)idx * DD + c * 8;
      pg[j] = gclSrc + ((size_t)f * NG + g) * DD + c * 8;
    } else { pa[j] = atomSrc; pg[j] = gclSrc; }
  }
  // B staging sources: 16 wave-insts/step, contiguous 1KB each (pre-chunked).
  const unsigned short* pb[4];
  {
    const unsigned short* WtF = Wt + (size_t)f * (16384 * 8);
#pragma unroll
    for (int j = 0; j < 4; ++j)
      pb[j] = WtF + (size_t)((j * 4 + wid) * 64 + lane) * 8;
  }

  auto stage = [&](int buf, int ks) {
#pragma unroll
    for (int j = 0; j < 2; ++j) {
      int q = j * 4 + wid;
      if (q < 6) {
        const unsigned short* src = (ks < 8) ? (pa[j] + ks * BK) : (pg[j] + (ks - 8) * BK);
        gld_lds16(src, &u.s.A[buf][q * 512]);
      }
    }
#pragma unroll
    for (int j = 0; j < 4; ++j)
      gld_lds16(pb[j] + (size_t)ks * 8192, &u.s.B[buf][(j * 4 + wid) * 512]);
  };

  f32x4 acc[6][4];
#pragma unroll
  for (int m = 0; m < 6; ++m)
#pragma unroll
    for (int n = 0; n < 4; ++n) acc[m][n] = (f32x4)0.f;

  stage(0, 0);
#pragma unroll
  for (int ks = 0; ks < NSTEP; ++ks) {
    const int cur = ks & 1;
    __syncthreads();
    if (ks + 1 < NSTEP) stage(cur ^ 1, ks + 1);
    s16x8 bv[4];
#pragma unroll
    for (int n = 0; n < 4; ++n)
      bv[n] = *(const s16x8*)&u.s.B[cur][(hi * 256 + wid * 64 + n * 16 + lo) * 8];
#pragma unroll
    for (int m = 0; m < 6; ++m) {
      s16x8 av = *(const s16x8*)&u.s.A[cur][(hi * 96 + m * 16 + lo) * 8];
#pragma unroll
      for (int n = 0; n < 4; ++n)
        acc[m][n] = __builtin_amdgcn_mfma_f32_16x16x32_bf16(av, bv[n], acc[m][n], 0, 0, 0);
    }
  }

  // ---- epilogue: two 128-col passes; pass p owned by waves {2p, 2p+1} ----
#pragma unroll
  for (int p = 0; p < 2; ++p) {
    __syncthreads();
    if ((wid >> 1) == p) {
      const int lc0 = (wid & 1) * 64;
      float bias_n[4];
#pragma unroll
      for (int n = 0; n < 4; ++n)
        bias_n[n] = bias[(size_t)f * DD + wid * 64 + n * 16 + lo];
#pragma unroll
      for (int m = 0; m < 6; ++m)
#pragma unroll
        for (int n = 0; n < 4; ++n) {
          int col = lc0 + n * 16 + lo;
#pragma unroll
          for (int r = 0; r < 4; ++r) {
            int row = m * 16 + hi * 4 + r;   // C/D: col = lane&15, row = (lane>>4)*4 + reg
            u.gc[row * 130 + col] = fmaxf(acc[m][n][r] + bias_n[n], 0.f);
          }
        }
    }
    __syncthreads();
    if (EPI == 0) {
      int nvg = ((MM - m0 < BM) ? (MM - m0) : BM) / 3;
      for (int e = tid; e < 32 * 128; e += 256) {
        int grp = e >> 7, col = e & 127;
        if (grp < nvg) {
          float v = fmaxf(fmaxf(u.gc[(grp * 3 + 0) * 130 + col],
                                u.gc[(grp * 3 + 1) * 130 + col]),
                          u.gc[(grp * 3 + 2) * 130 + col]);
          gclOut[((size_t)f * NG + (size_t)(m0 / 3 + grp)) * DD + p * 128 + col] = f2bf(v);
        }
      }
    } else if (EPI == 1) {
      for (int e = tid; e < BM * 16; e += 256) {
        int row = e >> 4, part = e & 15;
        if (m0 + row < MM) {
          uint32_t rk = rank_lds[row];
          union { unsigned short h[8]; uint4 u4; } o;
#pragma unroll
          for (int j = 0; j < 8; ++j) o.h[j] = f2bf(u.gc[row * 130 + part * 8 + j]);
          *(uint4*)&fiBuf[(size_t)rk * NO + p * 128 + part * 8] = o.u4;
        }
      }
    } else {
      for (int e = tid; e < BM * 128; e += 256) {
        int row = e >> 7, col = e & 127;
        if (m0 + row < MM) {
          int idx = idx_lds[row];
          atomicMax((unsigned int*)&atomOut[(size_t)idx * DD + p * 128 + col],
                    __float_as_uint(u.gc[row * 130 + col]));
        }
      }
    }
  }
}

extern "C" void kernel_launch(void* const* d_in, const int* in_sizes, int n_in,
                              void* d_out, int out_size, void* d_ws, size_t ws_size,
                              hipStream_t stream) {
  const float* x  = (const float*)d_in[0];
  const int*   gi = (const int*)d_in[1];
  const float* fg = (const float*)d_in[2];
  const float* WM = (const float*)d_in[3];
  const float* bM = (const float*)d_in[4];
  const float* WU = (const float*)d_in[5];
  const float* bU = (const float*)d_in[6];
  float* out = (float*)d_out;

  char* ws = (char*)d_ws;
  size_t off_b = 0;
  auto alloc = [&](size_t b) { char* p = ws + off_b; off_b += (b + 255) & ~(size_t)255; return p; };
  unsigned short* gcl0   = (unsigned short*)alloc((size_t)NF * NG * DD * 2);   // 102.4 MB
  unsigned short* gcl1   = (unsigned short*)alloc((size_t)NF * NG * DD * 2);   // 102.4 MB
  unsigned short* atomB  = (unsigned short*)alloc((size_t)NA * DD * 2);        // 25.6 MB
  unsigned short* atomB2 = (unsigned short*)alloc((size_t)NA * DD * 2);        // 25.6 MB
  unsigned short* Wt     = (unsigned short*)alloc((size_t)3 * NF * 16384 * 16);// 3.1 MB
  uint32_t* cnt  = (uint32_t*)alloc((size_t)NA * 4);
  uint32_t* offA = (uint32_t*)alloc((size_t)(NA + 1) * 4);
  uint32_t* bump = (uint32_t*)alloc((size_t)NA * 4);
  uint32_t* rank = (uint32_t*)alloc((size_t)TOT * 4);                           // 2.4 MB
  unsigned short* fiBuf = (unsigned short*)alloc((size_t)TOT * NO * 2);         // 307.2 MB
  const bool useSort = ws_size >= off_b;

  const unsigned short* WtM0 = Wt;
  const unsigned short* WtU0 = Wt + (size_t)NF * 16384 * 8;
  const unsigned short* WtU1 = Wt + (size_t)2 * NF * 16384 * 8;
  const float* bU1 = bU + (size_t)NF * DD;

  cvt_f32_bf16<<<(NA * DD / 4 + 255) / 256, 256, 0, stream>>>(x, atomB, NA * DD / 4);
  cvt_f32_bf16<<<(NF * NG * DD / 4 + 255) / 256, 256, 0, stream>>>(fg, gcl0, NF * NG * DD / 4);
  prep_w<<<(3 * NF * 16384 + 255) / 256, 256, 0, stream>>>(WM, WU, Wt);

  if (useSort) {
    hipMemsetAsync(cnt, 0, (size_t)NA * 4, stream);
    sort_count<<<(TOT + 255) / 256, 256, 0, stream>>>(gi, cnt);
    sort_scan<<<1, 1024, 0, stream>>>(cnt, offA, bump);
    sort_fill<<<(TOT + 255) / 256, 256, 0, stream>>>(gi, bump, rank);

    // layer 0
    fgnn_gemm<0><<<dim3(MT, NF), 256, 0, stream>>>(atomB, gcl0, WtM0, gi, bM,
                                                   nullptr, gcl1, nullptr, nullptr);
    fgnn_gemm<1><<<dim3(MT, NF), 256, 0, stream>>>(atomB, gcl0, WtU0, gi, bU,
                                                   nullptr, nullptr, fiBuf, rank);
    reduce_max<0><<<(NA + 3) / 4, 256, 0, stream>>>(fiBuf, offA, atomB2, nullptr);
    // layer 1
    fgnn_gemm<1><<<dim3(MT, NF), 256, 0, stream>>>(atomB2, gcl1, WtU1, gi, bU1,
                                                   nullptr, nullptr, fiBuf, rank);
    reduce_max<1><<<(NA + 3) / 4, 256, 0, stream>>>(fiBuf, offA, nullptr, out);
  } else {
    // atomic fallback
    hipMemsetAsync(d_out, 0, (size_t)NA * DD * 4, stream);
    fgnn_gemm<0><<<dim3(MT, NF), 256, 0, stream>>>(atomB, gcl0, WtM0, gi, bM,
                                                   nullptr, gcl1, nullptr, nullptr);
    fgnn_gemm<2><<<dim3(MT, NF), 256, 0, stream>>>(atomB, gcl0, WtU0, gi, bU,
                                                   out, nullptr, nullptr, nullptr);
    cvt_f32_bf16<<<(NA * DD / 4 + 255) / 256, 256, 0, stream>>>(out, atomB2, NA * DD / 4);
    hipMemsetAsync(d_out, 0, (size_t)NA * DD * 4, stream);
    fgnn_gemm<2><<<dim3(MT, NF), 256, 0, stream>>>(atomB2, gcl1, WtU1, gi, bU1,
                                                   out, nullptr, nullptr, nullptr);
  }
}

// Round 6
// 1077.416 us; speedup vs baseline: 1.7393x; 1.2848x over previous
//
#include <hip/hip_runtime.h>
#include <stdint.h>

#define NA 50000          // atoms (== NG, cliques per formula)
#define NAP 50016         // padded rows = 521 * 96
#define DD 256
#define NF 4
#define NG 50000
#define MM 150000         // rows per formula
#define TOT 600000        // total occurrence rows
#define BM 96
#define BK 32
#define NSTEP 8           // K = 256
#define MT 521            // NAP / BM

typedef __attribute__((ext_vector_type(8))) short s16x8;
typedef __attribute__((ext_vector_type(4))) float f32x4;

__device__ __forceinline__ unsigned short f2bf(float f) {
  union { float f; uint32_t u; } v; v.f = f;
  return (unsigned short)((v.u + 0x7FFFu + ((v.u >> 16) & 1u)) >> 16);  // RNE
}
__device__ __forceinline__ float bf2f(unsigned short h) {
  union { uint32_t u; float f; } v; v.u = ((uint32_t)h) << 16; return v.f;
}
__device__ __forceinline__ void gld_lds16(const void* g, void* l) {
  __builtin_amdgcn_global_load_lds(
      (const __attribute__((address_space(1))) uint32_t*)g,
      (__attribute__((address_space(3))) uint32_t*)l, 16, 0, 0);
}

// f32 [nb][NA][256] -> tiled bf16 [nb][NAP/96][32][96][8]; pad rows zeroed.
// Tiled linear offset for (grow, col): ((tile*32 + col/8)*96 + grow%96)*8 + col%8
__global__ void cvt_tile(const float* __restrict__ src, unsigned short* __restrict__ dst, int nb) {
  int t = blockIdx.x * 256 + threadIdx.x;          // t = (b*NAP + grow)*32 + cc
  if (t >= nb * NAP * 32) return;
  int cc = t & 31;
  int rem = t >> 5;
  int b = rem / NAP;
  int grow = rem - b * NAP;
  int tile = grow / BM, row = grow - tile * BM;
  unsigned short* d = dst + (size_t)b * NAP * 256 + ((size_t)(tile * 32 + cc) * BM + row) * 8;
  union { unsigned short h[8]; uint4 u; } o;
  if (grow < NA) {
    const float* s = src + ((size_t)b * NA + grow) * 256 + cc * 8;
    const float4 v0 = *(const float4*)s;
    const float4 v1 = *(const float4*)(s + 4);
    o.h[0] = f2bf(v0.x); o.h[1] = f2bf(v0.y); o.h[2] = f2bf(v0.z); o.h[3] = f2bf(v0.w);
    o.h[4] = f2bf(v1.x); o.h[5] = f2bf(v1.y); o.h[6] = f2bf(v1.z); o.h[7] = f2bf(v1.w);
  } else {
    o.u = make_uint4(0, 0, 0, 0);
  }
  *(uint4*)d = o.u;
}

// Weight pre-chunking. Slot layout per (f, nt): [kb=0..7][c=0..3][n=0..255], slot = 8 bf16,
// value[e] = W[k = kb*32 + c*8 + e][n]. Memory order (slots):
//   [0,65536)        top0: [f][nt]  nt0 = W_M[0] rows<256, nt1 = W_U[0] rows<256
//   [65536,131072)   bot0: same with rows 256..511
//   [131072,163840)  top1: [f]      W_U[1] rows<256
//   [163840,196608)  bot1: [f]      W_U[1] rows 256..511
__global__ void prep_w(const float* __restrict__ WM, const float* __restrict__ WU,
                       unsigned short* __restrict__ Wt) {
  int t = blockIdx.x * 256 + threadIdx.x;
  if (t >= 196608) return;
  const float* src;
  if (t < 131072) {
    int e = t & 65535;
    int f = e >> 14, nt = (e >> 13) & 1, r = e & 8191;
    int k = ((r >> 10) << 5) + (((r >> 8) & 3) << 3) + ((t >> 16) << 8);  // +256 for bot
    int n = r & 255;
    src = (nt ? WU : WM) + ((size_t)f * 512 + k) * 256 + n;
  } else {
    int e = t - 131072;
    int bot = e >> 15;           // 0 = top1, 1 = bot1
    e &= 32767;
    int f = e >> 13, r = e & 8191;
    int k = ((r >> 10) << 5) + (((r >> 8) & 3) << 3) + (bot << 8);
    int n = r & 255;
    src = WU + ((size_t)(NF + f) * 512 + k) * 256 + n;
  }
  union { unsigned short h[8]; uint4 u; } o;
#pragma unroll
  for (int e2 = 0; e2 < 8; ++e2) o.h[e2] = f2bf(src[(size_t)e2 * 256]);
  ((uint4*)Wt)[t] = o.u;
}

// ---- counting-sort CSR of flat_idx: off[a]..off[a+1] lists occurrence ids t ----
__global__ void sort_count(const int* __restrict__ gi, uint32_t* __restrict__ cnt) {
  int t = blockIdx.x * 256 + threadIdx.x;
  if (t < TOT) atomicAdd(&cnt[gi[t]], 1u);
}
__global__ void sort_scan(const uint32_t* __restrict__ cnt, uint32_t* __restrict__ off,
                          uint32_t* __restrict__ bump) {
  __shared__ uint32_t part[1024];
  const int t = threadIdx.x;
  const int CH = 49;
  int lo = t * CH, hi = lo + CH; if (hi > NA) hi = NA;
  uint32_t s = 0;
  for (int i = lo; i < hi; ++i) s += cnt[i];
  part[t] = s;
  __syncthreads();
  for (int d = 1; d < 1024; d <<= 1) {
    uint32_t v = (t >= d) ? part[t - d] : 0u;
    __syncthreads();
    part[t] += v;
    __syncthreads();
  }
  uint32_t run = (t == 0) ? 0u : part[t - 1];
  for (int i = lo; i < hi; ++i) { off[i] = run; bump[i] = run; run += cnt[i]; }
  if (t == 1023) off[NA] = part[1023];
}
__global__ void sort_fill(const int* __restrict__ gi, uint32_t* __restrict__ bump,
                          uint32_t* __restrict__ occList) {
  int t = blockIdx.x * 256 + threadIdx.x;
  if (t < TOT) { uint32_t r = atomicAdd(&bump[gi[t]], 1u); occList[r] = (uint32_t)t; }
}

// Dense tiled GEMM: P[f] = A[f or atoms] @ W[f][nt], 96x256 per block, BK=32, K=256.
// A is pre-tiled so staging src = A + mt*24576 + ks*3072 + slot*8 (contiguous 1KB/inst).
// z = blockIdx.z: f = z&3; z<4 -> atom side (out Pa), z>=4 -> gcl side (out Pg).
template <int NB>
__global__ __launch_bounds__(256, 3)
void pgemm(const unsigned short* __restrict__ Aatom,
           const unsigned short* __restrict__ Agcl,
           const unsigned short* __restrict__ Wtop,
           const unsigned short* __restrict__ Wbot,
           unsigned short* __restrict__ Pa,
           unsigned short* __restrict__ Pg)
{
  const int mt = blockIdx.x, nt = blockIdx.y, z = blockIdx.z;
  const int f = z & 3, side = z >> 2;
  const int tid = threadIdx.x, lane = tid & 63, wid = tid >> 6;
  const int hi = lane >> 4, lo = lane & 15;
  constexpr int RW = NB * 256;

  const unsigned short* A = (side ? (Agcl + (size_t)f * NAP * 256) : Aatom) + (size_t)mt * 24576;
  const unsigned short* W = (side ? Wbot : Wtop) + (size_t)(f * NB + nt) * 65536;
  unsigned short* P = (side ? Pg : Pa) + ((size_t)f * NAP + (size_t)mt * BM) * RW + nt * 256;

  __shared__ union U {
    struct { unsigned short A[2][3072]; unsigned short B[2][8192]; } s;  // 12KB + 32KB
    float gc[BM * 130];                                                   // 49.9KB
  } u;

  auto stage = [&](int buf, int ks) {
#pragma unroll
    for (int j = 0; j < 2; ++j) {
      int q = j * 4 + wid;
      if (q < 6)
        gld_lds16(A + ks * 3072 + (q * 64 + lane) * 8, &u.s.A[buf][q * 512]);
    }
#pragma unroll
    for (int j = 0; j < 4; ++j)
      gld_lds16(W + ks * 8192 + ((j * 4 + wid) * 64 + lane) * 8, &u.s.B[buf][(j * 4 + wid) * 512]);
  };

  f32x4 acc[6][4];
#pragma unroll
  for (int m = 0; m < 6; ++m)
#pragma unroll
    for (int n = 0; n < 4; ++n) acc[m][n] = (f32x4)0.f;

  stage(0, 0);
#pragma unroll
  for (int ks = 0; ks < NSTEP; ++ks) {
    const int cur = ks & 1;
    __syncthreads();
    if (ks + 1 < NSTEP) stage(cur ^ 1, ks + 1);
    s16x8 bv[4];
#pragma unroll
    for (int n = 0; n < 4; ++n)
      bv[n] = *(const s16x8*)&u.s.B[cur][(hi * 256 + wid * 64 + n * 16 + lo) * 8];
#pragma unroll
    for (int m = 0; m < 6; ++m) {
      s16x8 av = *(const s16x8*)&u.s.A[cur][(hi * 96 + m * 16 + lo) * 8];
#pragma unroll
      for (int n = 0; n < 4; ++n)
        acc[m][n] = __builtin_amdgcn_mfma_f32_16x16x32_bf16(av, bv[n], acc[m][n], 0, 0, 0);
    }
  }

  // epilogue: raw P store (no bias/relu), two 128-col passes via LDS transpose
#pragma unroll
  for (int p = 0; p < 2; ++p) {
    __syncthreads();
    if ((wid >> 1) == p) {
      const int lc0 = (wid & 1) * 64;
#pragma unroll
      for (int m = 0; m < 6; ++m)
#pragma unroll
        for (int n = 0; n < 4; ++n) {
          int col = lc0 + n * 16 + lo;
#pragma unroll
          for (int r = 0; r < 4; ++r)
            u.gc[(m * 16 + hi * 4 + r) * 130 + col] = acc[m][n][r];
        }
    }
    __syncthreads();
    for (int e = tid; e < BM * 16; e += 256) {
      int row = e >> 4, part = e & 15;
      union { unsigned short h[8]; uint4 u4; } o;
#pragma unroll
      for (int j = 0; j < 8; ++j) o.h[j] = f2bf(u.gc[row * 130 + part * 8 + j]);
      *(uint4*)&P[(size_t)row * RW + p * 128 + part * 8] = o.u4;
    }
  }
}

// L0 message combine: gcl1[f][g] = relu(max_s Pa_M[idx[f,g,s]] + Pg_M[f][g] + bM[f]).
// One wave per clique; lane covers 4 cols. Output tiled bf16.
__global__ __launch_bounds__(256)
void msg_combine(const unsigned short* __restrict__ Pa,   // [4][NAP][512], cols 0..255
                 const unsigned short* __restrict__ Pg,   // [4][NAP][512], cols 0..255
                 const int* __restrict__ gIdx,
                 const float* __restrict__ bM,
                 unsigned short* __restrict__ gclT1)      // tiled [4][NAP][256]
{
  const int wv = blockIdx.x * 4 + (threadIdx.x >> 6);     // clique id, < 200000
  const int lane = threadIdx.x & 63;
  const int f = wv / NG, g = wv - f * NG;
  const int c = lane * 4;
  const int* ip = gIdx + (size_t)f * MM + g * 3;
  int i0 = ip[0], i1 = ip[1], i2 = ip[2];
  const unsigned short* PaF = Pa + (size_t)f * NAP * 512;
  union { unsigned short h[4]; uint2 u; } a0, a1, a2, pg, o;
  a0.u = *(const uint2*)(PaF + (size_t)i0 * 512 + c);
  a1.u = *(const uint2*)(PaF + (size_t)i1 * 512 + c);
  a2.u = *(const uint2*)(PaF + (size_t)i2 * 512 + c);
  pg.u = *(const uint2*)(Pg + ((size_t)f * NAP + g) * 512 + c);
  const float4 b = *(const float4*)(bM + f * 256 + c);
  const float bb[4] = {b.x, b.y, b.z, b.w};
#pragma unroll
  for (int j = 0; j < 4; ++j) {
    float m = fmaxf(fmaxf(bf2f(a0.h[j]), bf2f(a1.h[j])), bf2f(a2.h[j]));
    o.h[j] = f2bf(fmaxf(m + bf2f(pg.h[j]) + bb[j], 0.f));
  }
  int tile = g / BM, row = g - tile * BM;
  *(uint2*)(gclT1 + (size_t)f * NAP * 256 +
            ((size_t)(tile * 32 + (lane >> 1)) * BM + row) * 8 + (lane & 1) * 4) = o.u;
}

// Update combine: out[a] = max(0, max_occ(Pa_U[f][a] + Pg_U[f][g] + bU[f])).
// One wave per atom; CSR occurrence list. L=0 -> tiled bf16 out; L=1 -> f32 d_out.
template <int L>
__global__ __launch_bounds__(256)
void upd_combine(const unsigned short* __restrict__ Pa,
                 const unsigned short* __restrict__ Pg,
                 const uint32_t* __restrict__ offA,
                 const uint32_t* __restrict__ occList,
                 const float* __restrict__ bU,            // layer-offset [4][256]
                 unsigned short* __restrict__ outT,
                 float* __restrict__ outF)
{
  constexpr int RW = (L == 0) ? 512 : 256;
  constexpr int CO = (L == 0) ? 256 : 0;
  const int a = blockIdx.x * 4 + (threadIdx.x >> 6);      // < 50000
  const int lane = threadIdx.x & 63;
  const int c = lane * 4;
  float pa[4][4];
#pragma unroll
  for (int f = 0; f < 4; ++f) {
    union { unsigned short h[4]; uint2 u; } v;
    v.u = *(const uint2*)(Pa + ((size_t)f * NAP + a) * RW + CO + c);
    const float4 b = *(const float4*)(bU + f * 256 + c);
    pa[f][0] = bf2f(v.h[0]) + b.x; pa[f][1] = bf2f(v.h[1]) + b.y;
    pa[f][2] = bf2f(v.h[2]) + b.z; pa[f][3] = bf2f(v.h[3]) + b.w;
  }
  float zm[4] = {0.f, 0.f, 0.f, 0.f};                     // 0-init = relu floor + empty case
  const uint32_t s = offA[a], e = offA[a + 1];
  for (uint32_t base = s; base < e; base += 64) {
    int nv = (int)(e - base); if (nv > 64) nv = 64;
    uint32_t tmine = (base + lane < e) ? occList[base + lane] : 0u;
    for (int k = 0; k < nv; ++k) {
      uint32_t t = __shfl(tmine, k);
      int f = (int)(t / (uint32_t)MM);
      int g = (int)((t - (uint32_t)f * MM) / 3u);
      union { unsigned short h[4]; uint2 u; } v;
      v.u = *(const uint2*)(Pg + ((size_t)f * NAP + g) * RW + CO + c);
#pragma unroll
      for (int j = 0; j < 4; ++j)
        zm[j] = fmaxf(zm[j], pa[f][j] + bf2f(v.h[j]));
    }
  }
  if (L == 0) {
    union { unsigned short h[4]; uint2 u; } o;
#pragma unroll
    for (int j = 0; j < 4; ++j) o.h[j] = f2bf(zm[j]);
    int tile = a / BM, row = a - tile * BM;
    *(uint2*)(outT + ((size_t)(tile * 32 + (lane >> 1)) * BM + row) * 8 + (lane & 1) * 4) = o.u;
  } else {
    float4 o; o.x = zm[0]; o.y = zm[1]; o.z = zm[2]; o.w = zm[3];
    *(float4*)(outF + (size_t)a * 256 + c) = o;
  }
}

extern "C" void kernel_launch(void* const* d_in, const int* in_sizes, int n_in,
                              void* d_out, int out_size, void* d_ws, size_t ws_size,
                              hipStream_t stream) {
  const float* x  = (const float*)d_in[0];
  const int*   gi = (const int*)d_in[1];
  const float* fg = (const float*)d_in[2];
  const float* WM = (const float*)d_in[3];
  const float* bM = (const float*)d_in[4];
  const float* WU = (const float*)d_in[5];
  const float* bU = (const float*)d_in[6];
  float* out = (float*)d_out;

  char* ws = (char*)d_ws;
  size_t off_b = 0;
  auto alloc = [&](size_t b) { char* p = ws + off_b; off_b += (b + 255) & ~(size_t)255; return p; };
  unsigned short* atomT = (unsigned short*)alloc((size_t)NAP * 256 * 2);      // 25.6 MB (reused as atomT2)
  unsigned short* gclT  = (unsigned short*)alloc((size_t)NF * NAP * 256 * 2); // 102.4 MB (gcl0 then gcl1)
  unsigned short* P0a   = (unsigned short*)alloc((size_t)NF * NAP * 512 * 2); // 204.9 MB (reused as P1a|P1g)
  unsigned short* P0g   = (unsigned short*)alloc((size_t)NF * NAP * 512 * 2); // 204.9 MB
  unsigned short* Wt    = (unsigned short*)alloc((size_t)196608 * 16);        // 3.15 MB
  uint32_t* cnt     = (uint32_t*)alloc((size_t)NA * 4);
  uint32_t* offA    = (uint32_t*)alloc((size_t)(NA + 1) * 4);
  uint32_t* bump    = (uint32_t*)alloc((size_t)NA * 4);
  uint32_t* occList = (uint32_t*)alloc((size_t)TOT * 4);                      // total ~544 MB

  const unsigned short* Wt0top = Wt;
  const unsigned short* Wt0bot = Wt + (size_t)65536 * 8;
  const unsigned short* Wt1top = Wt + (size_t)131072 * 8;
  const unsigned short* Wt1bot = Wt + (size_t)163840 * 8;
  unsigned short* P1a = P0a;
  unsigned short* P1g = P0a + (size_t)NF * NAP * 256;

  cvt_tile<<<(1 * NAP * 32 + 255) / 256, 256, 0, stream>>>(x, atomT, 1);
  cvt_tile<<<(NF * NAP * 32 + 255) / 256, 256, 0, stream>>>(fg, gclT, NF);
  prep_w<<<768, 256, 0, stream>>>(WM, WU, Wt);
  hipMemsetAsync(cnt, 0, (size_t)NA * 4, stream);
  sort_count<<<(TOT + 255) / 256, 256, 0, stream>>>(gi, cnt);
  sort_scan<<<1, 1024, 0, stream>>>(cnt, offA, bump);
  sort_fill<<<(TOT + 255) / 256, 256, 0, stream>>>(gi, bump, occList);

  // layer 0: Pa = atom @ [WM_top|WU_top], Pg = gcl0 @ [WM_bot|WU_bot]
  pgemm<2><<<dim3(MT, 2, 8), 256, 0, stream>>>(atomT, gclT, Wt0top, Wt0bot, P0a, P0g);
  msg_combine<<<NF * NG / 4, 256, 0, stream>>>(P0a, P0g, gi, bM, gclT);          // gclT := gcl1
  upd_combine<0><<<NA / 4, 256, 0, stream>>>(P0a, P0g, offA, occList, bU, atomT, nullptr);  // atomT := atom1

  // layer 1: Pa = atom1 @ WU1_top, Pg = gcl1 @ WU1_bot
  pgemm<1><<<dim3(MT, 1, 8), 256, 0, stream>>>(atomT, gclT, Wt1top, Wt1bot, P1a, P1g);
  upd_combine<1><<<NA / 4, 256, 0, stream>>>(P1a, P1g, offA, occList, bU + 1024, nullptr, out);
}

// Round 7
// 1040.163 us; speedup vs baseline: 1.8016x; 1.0358x over previous
//
#include <hip/hip_runtime.h>
#include <stdint.h>

#define NA 50000
#define DD 256
#define NF 4
#define NG 50000
#define MM 150000
#define TOT 600000
#define NAP2 50048        // 391 * 128
#define NT2 391
#define KK 256            // K per GEMM (split concat)

typedef __attribute__((ext_vector_type(8))) short s16x8;
typedef __attribute__((ext_vector_type(4))) float f32x4;

__device__ __forceinline__ unsigned short f2bf(float f) {
  union { float f; uint32_t u; } v; v.f = f;
  return (unsigned short)((v.u + 0x7FFFu + ((v.u >> 16) & 1u)) >> 16);  // RNE
}
__device__ __forceinline__ float bf2f(unsigned short h) {
  union { uint32_t u; float f; } v; v.u = ((uint32_t)h) << 16; return v.f;
}
__device__ __forceinline__ void gld_lds16(const void* g, void* l) {
  __builtin_amdgcn_global_load_lds(
      (const __attribute__((address_space(1))) uint32_t*)g,
      (__attribute__((address_space(3))) uint32_t*)l, 16, 0, 0);
}

// f32 [b][50000][256] -> tiled bf16 [b][tile=grow/128][kb][c][row=grow%128][8]
// value = src[grow][kb*32 + c*8 + e]; pad rows (>=50000) zeroed.
__global__ void cvt_tile(const float* __restrict__ src, unsigned short* __restrict__ dst) {
  int blk = blockIdx.x;                 // ((b*391 + tile)*8 + kb)*2 + cp
  int cp = blk & 1, kb = (blk >> 1) & 7, rem = blk >> 4;
  int tile = rem % NT2, b = rem / NT2;
  int cl = threadIdx.x >> 7, row = threadIdx.x & 127;
  int c = cp * 2 + cl;
  int grow = tile * 128 + row;
  union { unsigned short h[8]; uint4 u; } o;
  if (grow < NA) {
    const float* s = src + ((size_t)b * NA + grow) * 256 + kb * 32 + c * 8;
    float4 v0 = *(const float4*)s, v1 = *(const float4*)(s + 4);
    o.h[0]=f2bf(v0.x); o.h[1]=f2bf(v0.y); o.h[2]=f2bf(v0.z); o.h[3]=f2bf(v0.w);
    o.h[4]=f2bf(v1.x); o.h[5]=f2bf(v1.y); o.h[6]=f2bf(v1.z); o.h[7]=f2bf(v1.w);
  } else o.u = make_uint4(0, 0, 0, 0);
  *(uint4*)(dst + (size_t)b * NAP2 * 256 +
            ((size_t)(tile * 8 + kb) * 512 + c * 128 + row) * 8) = o.u;
}

// Weight pre-chunk (unchanged layout, slot = [kb][c][n], value[e]=W[kb*32+c*8+e][n]):
//   slots [0,65536): top0 [f][nt]; [65536,131072): bot0; [131072,163840): top1 [f];
//   [163840,196608): bot1 [f]
__global__ void prep_w(const float* __restrict__ WM, const float* __restrict__ WU,
                       unsigned short* __restrict__ Wt) {
  int t = blockIdx.x * 256 + threadIdx.x;
  if (t >= 196608) return;
  const float* src;
  if (t < 131072) {
    int e = t & 65535;
    int f = e >> 14, nt = (e >> 13) & 1, r = e & 8191;
    int k = ((r >> 10) << 5) + (((r >> 8) & 3) << 3) + ((t >> 16) << 8);
    int n = r & 255;
    src = (nt ? WU : WM) + ((size_t)f * 512 + k) * 256 + n;
  } else {
    int e = t - 131072;
    int bot = e >> 15;
    e &= 32767;
    int f = e >> 13, r = e & 8191;
    int k = ((r >> 10) << 5) + (((r >> 8) & 3) << 3) + (bot << 8);
    int n = r & 255;
    src = WU + ((size_t)(NF + f) * 512 + k) * 256 + n;
  }
  union { unsigned short h[8]; uint4 u; } o;
#pragma unroll
  for (int e2 = 0; e2 < 8; ++e2) o.h[e2] = f2bf(src[(size_t)e2 * 256]);
  ((uint4*)Wt)[t] = o.u;
}

// ---- counting-sort CSR of flat_idx ----
__global__ void sort_count(const int* __restrict__ gi, uint32_t* __restrict__ cnt) {
  int t = blockIdx.x * 256 + threadIdx.x;
  if (t < TOT) atomicAdd(&cnt[gi[t]], 1u);
}
__global__ void sort_scan(const uint32_t* __restrict__ cnt, uint32_t* __restrict__ off,
                          uint32_t* __restrict__ bump) {
  __shared__ uint32_t part[1024];
  const int t = threadIdx.x;
  const int CH = 49;
  int lo = t * CH, hi = lo + CH; if (hi > NA) hi = NA;
  uint32_t s = 0;
  for (int i = lo; i < hi; ++i) s += cnt[i];
  part[t] = s;
  __syncthreads();
  for (int d = 1; d < 1024; d <<= 1) {
    uint32_t v = (t >= d) ? part[t - d] : 0u;
    __syncthreads();
    part[t] += v;
    __syncthreads();
  }
  uint32_t run = (t == 0) ? 0u : part[t - 1];
  for (int i = lo; i < hi; ++i) { off[i] = run; bump[i] = run; run += cnt[i]; }
  if (t == 1023) off[NA] = part[1023];
}
__global__ void sort_fill(const int* __restrict__ gi, uint32_t* __restrict__ bump,
                          uint32_t* __restrict__ occList) {
  int t = blockIdx.x * 256 + threadIdx.x;
  if (t < TOT) { uint32_t r = atomicAdd(&bump[gi[t]], 1u); occList[r] = (uint32_t)t; }
}

// Persistent-W GEMM. One block owns one W matrix (128KB in LDS) and an M-chunk.
// A streamed via 3-deep 8KB ring, counted vmcnt(1), raw barriers.
// L=0: 16 W (side,f,nt), RW=512, 16 chunks. L=1: 8 W (side,f), RW=256, 32 chunks.
template <int L>
__global__ __launch_bounds__(512, 2)
void pgemm(const unsigned short* __restrict__ Aatom,
           const unsigned short* __restrict__ Agcl,
           const unsigned short* __restrict__ Wt,
           unsigned short* __restrict__ Pa,
           unsigned short* __restrict__ Pg)
{
  constexpr int RW = (L == 0) ? 512 : 256;
  const int ch = blockIdx.x, w = blockIdx.y;
  int side, f, nt;
  if (L == 0) { side = w >> 3; f = (w >> 1) & 3; nt = w & 1; }
  else        { side = w >> 2; f = w & 3; nt = 0; }
  int tbase, tcnt;
  if (L == 0) { tbase = (ch < 7) ? ch * 25 : 175 + (ch - 7) * 24; tcnt = (ch < 7) ? 25 : 24; }
  else        { tbase = (ch < 7) ? ch * 13 : 91 + (ch - 7) * 12;  tcnt = (ch < 7) ? 13 : 12; }

  const size_t wslot = (L == 0) ? ((size_t)side * 65536 + (size_t)(f * 2 + nt) * 8192)
                                : ((size_t)131072 + (size_t)side * 32768 + (size_t)f * 8192);
  const unsigned short* Wm = Wt + wslot * 8;
  const unsigned short* Ab = side ? (Agcl + (size_t)f * NAP2 * 256) : Aatom;
  unsigned short* P = (side ? Pg : Pa) + (size_t)f * NAP2 * RW + nt * 256;

  const int tid = threadIdx.x, lane = tid & 63, wid = tid >> 6;
  const int wm = wid >> 2, wn = wid & 3;     // 2x4 wave grid: 64 rows x 64 cols each
  const int hi = lane >> 4, lo = lane & 15;

  __shared__ unsigned short Wl[65536];       // 128 KB: whole W matrix
  __shared__ unsigned short Ar[3][4096];     // 3 x 8 KB A ring

  // stage W once: 16 rounds x (8 waves x 1KB)
#pragma unroll
  for (int r = 0; r < 16; ++r)
    gld_lds16(Wm + ((size_t)(r * 8 + wid) * 64 + lane) * 8, &Wl[(r * 8 + wid) * 512]);

  const unsigned short* as = Ab + (size_t)tbase * 32768 + (size_t)(wid * 64 + lane) * 8;
  const int NS = tcnt * 8;

  f32x4 acc[4][4];
#pragma unroll
  for (int m = 0; m < 4; ++m)
#pragma unroll
    for (int n = 0; n < 4; ++n) acc[m][n] = (f32x4)0.f;

  // prologue: 2 A-steps in flight
  gld_lds16(as, &Ar[0][wid * 512]);
  gld_lds16(as + 4096, &Ar[1][wid * 512]);

  for (int tl = 0; tl < tcnt; ++tl) {
    const int bt = (tl * 2) % 3;             // ring phase of this tile's kb=0
#pragma unroll
    for (int kb = 0; kb < 8; ++kb) {
      const int s = tl * 8 + kb;
      if (s == NS - 1) { asm volatile("s_waitcnt vmcnt(0)" ::: "memory"); }
      else             { asm volatile("s_waitcnt vmcnt(1)" ::: "memory"); }
      __builtin_amdgcn_sched_barrier(0);
      __builtin_amdgcn_s_barrier();
      __builtin_amdgcn_sched_barrier(0);

      if (kb == 0 && tl > 0) {
        // store previous tile (before staging, so counted waits never drain prefetch)
        const size_t rb = (size_t)(tbase + tl - 1) * 128 + wm * 64;
#pragma unroll
        for (int m = 0; m < 4; ++m)
#pragma unroll
          for (int n = 0; n < 4; ++n) {
            int col = wn * 64 + n * 16 + lo;
#pragma unroll
            for (int r = 0; r < 4; ++r) {
              P[(rb + m * 16 + hi * 4 + r) * RW + col] = f2bf(acc[m][n][r]);
              acc[m][n][r] = 0.f;
            }
          }
      }
      if (s + 2 < NS)
        gld_lds16(as + (size_t)(s + 2) * 4096, &Ar[(bt + ((kb + 2) % 3)) >= 3 ?
                  (bt + ((kb + 2) % 3)) - 3 : (bt + ((kb + 2) % 3))][wid * 512]);

      int buf = bt + (kb % 3); if (buf >= 3) buf -= 3;
      const unsigned short* Abuf = Ar[buf];
      s16x8 bv[4], av[4];
#pragma unroll
      for (int n = 0; n < 4; ++n)
        bv[n] = *(const s16x8*)&Wl[(kb * 1024 + hi * 256 + wn * 64 + n * 16 + lo) * 8];
#pragma unroll
      for (int m = 0; m < 4; ++m)
        av[m] = *(const s16x8*)&Abuf[(hi * 128 + wm * 64 + m * 16 + lo) * 8];
#pragma unroll
      for (int m = 0; m < 4; ++m)
#pragma unroll
        for (int n = 0; n < 4; ++n)
          acc[m][n] = __builtin_amdgcn_mfma_f32_16x16x32_bf16(av[m], bv[n], acc[m][n], 0, 0, 0);
    }
  }
  // final tile store (vmcnt fully drained on last step)
  {
    const size_t rb = (size_t)(tbase + tcnt - 1) * 128 + wm * 64;
#pragma unroll
    for (int m = 0; m < 4; ++m)
#pragma unroll
      for (int n = 0; n < 4; ++n) {
        int col = wn * 64 + n * 16 + lo;
#pragma unroll
        for (int r = 0; r < 4; ++r)
          P[(rb + m * 16 + hi * 4 + r) * RW + col] = f2bf(acc[m][n][r]);
      }
  }
}

// L0 message combine: gcl1[f][g] = relu(max_s Pa[idx[f,g,s]] + Pg[f][g] + bM[f]); tiled out.
__global__ __launch_bounds__(256)
void msg_combine(const unsigned short* __restrict__ Pa,
                 const unsigned short* __restrict__ Pg,
                 const int* __restrict__ gIdx,
                 const float* __restrict__ bM,
                 unsigned short* __restrict__ gclT1)
{
  const int wv = blockIdx.x * 4 + (threadIdx.x >> 6);     // < 4*50048
  const int lane = threadIdx.x & 63;
  const int f = wv / NAP2, g = wv - f * NAP2;
  const int tile = g >> 7, row = g & 127;
  const int kb = lane >> 3, c = (lane >> 1) & 3, e = (lane & 1) * 4;
  unsigned short* dp = gclT1 + (size_t)f * NAP2 * 256 +
                       ((size_t)(tile * 8 + kb) * 512 + c * 128 + row) * 8 + e;
  if (g >= NG) { *(uint2*)dp = make_uint2(0, 0); return; }
  const int cc = lane * 4;
  const int* ip = gIdx + (size_t)f * MM + g * 3;
  int i0 = ip[0], i1 = ip[1], i2 = ip[2];
  const unsigned short* PaF = Pa + (size_t)f * NAP2 * 512;
  union { unsigned short h[4]; uint2 u; } a0, a1, a2, pg, o;
  a0.u = *(const uint2*)(PaF + (size_t)i0 * 512 + cc);
  a1.u = *(const uint2*)(PaF + (size_t)i1 * 512 + cc);
  a2.u = *(const uint2*)(PaF + (size_t)i2 * 512 + cc);
  pg.u = *(const uint2*)(Pg + ((size_t)f * NAP2 + g) * 512 + cc);
  const float4 b = *(const float4*)(bM + f * 256 + cc);
  const float bb[4] = {b.x, b.y, b.z, b.w};
#pragma unroll
  for (int j = 0; j < 4; ++j) {
    float m = fmaxf(fmaxf(bf2f(a0.h[j]), bf2f(a1.h[j])), bf2f(a2.h[j]));
    o.h[j] = f2bf(fmaxf(m + bf2f(pg.h[j]) + bb[j], 0.f));
  }
  *(uint2*)dp = o.u;
}

// Update combine: out[a] = max(0, max_occ(Pa[f][a] + Pg[f][g] + bU[f])).
// L=0 -> tiled bf16 (next-layer A); L=1 -> f32 d_out.
template <int L>
__global__ __launch_bounds__(256)
void upd_combine(const unsigned short* __restrict__ Pa,
                 const unsigned short* __restrict__ Pg,
                 const uint32_t* __restrict__ offA,
                 const uint32_t* __restrict__ occList,
                 const float* __restrict__ bU,
                 unsigned short* __restrict__ outT,
                 float* __restrict__ outF)
{
  constexpr int RW = (L == 0) ? 512 : 256;
  constexpr int CO = (L == 0) ? 256 : 0;
  const int a = blockIdx.x * 4 + (threadIdx.x >> 6);
  const int lane = threadIdx.x & 63;
  const int c = lane * 4;
  if (L == 0 && a >= NA) {
    if (a < NAP2) {
      int tile = a >> 7, row = a & 127;
      int kb = lane >> 3, cq = (lane >> 1) & 3, e = (lane & 1) * 4;
      *(uint2*)(outT + ((size_t)(tile * 8 + kb) * 512 + cq * 128 + row) * 8 + e) = make_uint2(0, 0);
    }
    return;
  }
  if (a >= NA) return;
  float pa[4][4];
#pragma unroll
  for (int f = 0; f < 4; ++f) {
    union { unsigned short h[4]; uint2 u; } v;
    v.u = *(const uint2*)(Pa + ((size_t)f * NAP2 + a) * RW + CO + c);
    const float4 b = *(const float4*)(bU + f * 256 + c);
    pa[f][0] = bf2f(v.h[0]) + b.x; pa[f][1] = bf2f(v.h[1]) + b.y;
    pa[f][2] = bf2f(v.h[2]) + b.z; pa[f][3] = bf2f(v.h[3]) + b.w;
  }
  float zm[4] = {0.f, 0.f, 0.f, 0.f};
  const uint32_t s = offA[a], e = offA[a + 1];
  for (uint32_t base = s; base < e; base += 64) {
    int nv = (int)(e - base); if (nv > 64) nv = 64;
    uint32_t tmine = (base + lane < e) ? occList[base + lane] : 0u;
    for (int k = 0; k < nv; ++k) {
      uint32_t t = __shfl(tmine, k);
      int f = (int)(t / (uint32_t)MM);
      int g = (int)((t - (uint32_t)f * MM) / 3u);
      union { unsigned short h[4]; uint2 u; } v;
      v.u = *(const uint2*)(Pg + ((size_t)f * NAP2 + g) * RW + CO + c);
#pragma unroll
      for (int j = 0; j < 4; ++j)
        zm[j] = fmaxf(zm[j], pa[f][j] + bf2f(v.h[j]));
    }
  }
  if (L == 0) {
    union { unsigned short h[4]; uint2 u; } o;
#pragma unroll
    for (int j = 0; j < 4; ++j) o.h[j] = f2bf(zm[j]);
    int tile = a >> 7, row = a & 127;
    int kb = lane >> 3, cq = (lane >> 1) & 3, e2 = (lane & 1) * 4;
    *(uint2*)(outT + ((size_t)(tile * 8 + kb) * 512 + cq * 128 + row) * 8 + e2) = o.u;
  } else {
    float4 o; o.x = zm[0]; o.y = zm[1]; o.z = zm[2]; o.w = zm[3];
    *(float4*)(outF + (size_t)a * 256 + c) = o;
  }
}

extern "C" void kernel_launch(void* const* d_in, const int* in_sizes, int n_in,
                              void* d_out, int out_size, void* d_ws, size_t ws_size,
                              hipStream_t stream) {
  const float* x  = (const float*)d_in[0];
  const int*   gi = (const int*)d_in[1];
  const float* fg = (const float*)d_in[2];
  const float* WM = (const float*)d_in[3];
  const float* bM = (const float*)d_in[4];
  const float* WU = (const float*)d_in[5];
  const float* bU = (const float*)d_in[6];
  float* out = (float*)d_out;

  char* ws = (char*)d_ws;
  size_t off_b = 0;
  auto alloc = [&](size_t b) { char* p = ws + off_b; off_b += (b + 255) & ~(size_t)255; return p; };
  unsigned short* atomT = (unsigned short*)alloc((size_t)NAP2 * 256 * 2);      // 25.6 MB
  unsigned short* gclT  = (unsigned short*)alloc((size_t)NF * NAP2 * 256 * 2); // 102.5 MB
  unsigned short* P0a   = (unsigned short*)alloc((size_t)NF * NAP2 * 512 * 2); // 205 MB
  unsigned short* P0g   = (unsigned short*)alloc((size_t)NF * NAP2 * 512 * 2); // 205 MB
  unsigned short* Wt    = (unsigned short*)alloc((size_t)196608 * 16);         // 3.15 MB
  uint32_t* cnt     = (uint32_t*)alloc((size_t)NA * 4);
  uint32_t* offA    = (uint32_t*)alloc((size_t)(NA + 1) * 4);
  uint32_t* bump    = (uint32_t*)alloc((size_t)NA * 4);
  uint32_t* occList = (uint32_t*)alloc((size_t)TOT * 4);

  unsigned short* P1a = P0a;
  unsigned short* P1g = P0a + (size_t)NF * NAP2 * 256;

  cvt_tile<<<NT2 * 16, 256, 0, stream>>>(x, atomT);
  cvt_tile<<<NF * NT2 * 16, 256, 0, stream>>>(fg, gclT);
  prep_w<<<768, 256, 0, stream>>>(WM, WU, Wt);
  hipMemsetAsync(cnt, 0, (size_t)NA * 4, stream);
  sort_count<<<(TOT + 255) / 256, 256, 0, stream>>>(gi, cnt);
  sort_scan<<<1, 1024, 0, stream>>>(cnt, offA, bump);
  sort_fill<<<(TOT + 255) / 256, 256, 0, stream>>>(gi, bump, occList);

  // layer 0: persistent-W GEMMs (256 blocks, 1/CU)
  pgemm<0><<<dim3(16, 16), 512, 0, stream>>>(atomT, gclT, Wt, P0a, P0g);
  msg_combine<<<NF * NAP2 / 4, 256, 0, stream>>>(P0a, P0g, gi, bM, gclT);        // gclT := gcl1 (tiled)
  upd_combine<0><<<NAP2 / 4, 256, 0, stream>>>(P0a, P0g, offA, occList, bU, atomT, nullptr);

  // layer 1
  pgemm<1><<<dim3(32, 8), 512, 0, stream>>>(atomT, gclT, Wt, P1a, P1g);
  upd_combine<1><<<(NA + 3) / 4, 256, 0, stream>>>(P1a, P1g, offA, occList, bU + 1024, nullptr, out);
}

// Round 8
// 1005.617 us; speedup vs baseline: 1.8635x; 1.0344x over previous
//
#include <hip/hip_runtime.h>
#include <stdint.h>

#define NA 50000
#define DD 256
#define NF 4
#define NG 50000
#define MM 150000
#define TOT 600000
#define NAP2 50048        // 391 * 128
#define NT2 391
#define KK 256            // K per GEMM (split concat)

typedef __attribute__((ext_vector_type(8))) short s16x8;
typedef __attribute__((ext_vector_type(4))) float f32x4;

__device__ __forceinline__ unsigned short f2bf(float f) {
  union { float f; uint32_t u; } v; v.f = f;
  return (unsigned short)((v.u + 0x7FFFu + ((v.u >> 16) & 1u)) >> 16);  // RNE
}
__device__ __forceinline__ float bf2f(unsigned short h) {
  union { uint32_t u; float f; } v; v.u = ((uint32_t)h) << 16; return v.f;
}
__device__ __forceinline__ void gld_lds16(const void* g, void* l) {
  __builtin_amdgcn_global_load_lds(
      (const __attribute__((address_space(1))) uint32_t*)g,
      (__attribute__((address_space(3))) uint32_t*)l, 16, 0, 0);
}

// f32 [b][50000][256] -> tiled bf16 [b][tile=grow/128][kb][c][row=grow%128][8]
__global__ void cvt_tile(const float* __restrict__ src, unsigned short* __restrict__ dst) {
  int blk = blockIdx.x;                 // ((b*391 + tile)*8 + kb)*2 + cp
  int cp = blk & 1, kb = (blk >> 1) & 7, rem = blk >> 4;
  int tile = rem % NT2, b = rem / NT2;
  int cl = threadIdx.x >> 7, row = threadIdx.x & 127;
  int c = cp * 2 + cl;
  int grow = tile * 128 + row;
  union { unsigned short h[8]; uint4 u; } o;
  if (grow < NA) {
    const float* s = src + ((size_t)b * NA + grow) * 256 + kb * 32 + c * 8;
    float4 v0 = *(const float4*)s, v1 = *(const float4*)(s + 4);
    o.h[0]=f2bf(v0.x); o.h[1]=f2bf(v0.y); o.h[2]=f2bf(v0.z); o.h[3]=f2bf(v0.w);
    o.h[4]=f2bf(v1.x); o.h[5]=f2bf(v1.y); o.h[6]=f2bf(v1.z); o.h[7]=f2bf(v1.w);
  } else o.u = make_uint4(0, 0, 0, 0);
  *(uint4*)(dst + (size_t)b * NAP2 * 256 +
            ((size_t)(tile * 8 + kb) * 512 + c * 128 + row) * 8) = o.u;
}

// Weight pre-chunk: slot = [kb][c][n], value[e]=W[kb*32+c*8+e][n].
//   slots [0,65536): top0 [f][nt]; [65536,131072): bot0; [131072,163840): top1 [f];
//   [163840,196608): bot1 [f]
__global__ void prep_w(const float* __restrict__ WM, const float* __restrict__ WU,
                       unsigned short* __restrict__ Wt) {
  int t = blockIdx.x * 256 + threadIdx.x;
  if (t >= 196608) return;
  const float* src;
  if (t < 131072) {
    int e = t & 65535;
    int f = e >> 14, nt = (e >> 13) & 1, r = e & 8191;
    int k = ((r >> 10) << 5) + (((r >> 8) & 3) << 3) + ((t >> 16) << 8);
    int n = r & 255;
    src = (nt ? WU : WM) + ((size_t)f * 512 + k) * 256 + n;
  } else {
    int e = t - 131072;
    int bot = e >> 15;
    e &= 32767;
    int f = e >> 13, r = e & 8191;
    int k = ((r >> 10) << 5) + (((r >> 8) & 3) << 3) + (bot << 8);
    int n = r & 255;
    src = WU + ((size_t)(NF + f) * 512 + k) * 256 + n;
  }
  union { unsigned short h[8]; uint4 u; } o;
#pragma unroll
  for (int e2 = 0; e2 < 8; ++e2) o.h[e2] = f2bf(src[(size_t)e2 * 256]);
  ((uint4*)Wt)[t] = o.u;
}

// ---- counting-sort CSR of flat_idx ----
__global__ void sort_count(const int* __restrict__ gi, uint32_t* __restrict__ cnt) {
  int t = blockIdx.x * 256 + threadIdx.x;
  if (t < TOT) atomicAdd(&cnt[gi[t]], 1u);
}
__global__ void sort_scan(const uint32_t* __restrict__ cnt, uint32_t* __restrict__ off,
                          uint32_t* __restrict__ bump) {
  __shared__ uint32_t part[1024];
  const int t = threadIdx.x;
  const int CH = 49;
  int lo = t * CH, hi = lo + CH; if (hi > NA) hi = NA;
  uint32_t s = 0;
  for (int i = lo; i < hi; ++i) s += cnt[i];
  part[t] = s;
  __syncthreads();
  for (int d = 1; d < 1024; d <<= 1) {
    uint32_t v = (t >= d) ? part[t - d] : 0u;
    __syncthreads();
    part[t] += v;
    __syncthreads();
  }
  uint32_t run = (t == 0) ? 0u : part[t - 1];
  for (int i = lo; i < hi; ++i) { off[i] = run; bump[i] = run; run += cnt[i]; }
  if (t == 1023) off[NA] = part[1023];
}
__global__ void sort_fill(const int* __restrict__ gi, uint32_t* __restrict__ bump,
                          uint32_t* __restrict__ occList) {
  int t = blockIdx.x * 256 + threadIdx.x;
  if (t < TOT) { uint32_t r = atomicAdd(&bump[gi[t]], 1u); occList[r] = (uint32_t)t; }
}

// Persistent-W GEMM with swapped-operand MFMA and store-aware counted vmcnt.
// W (128KB) in LDS; A streamed through a 3x8KB ring, prefetch depth 2.
// Waits (in-order vmcnt positions): kb==1,2 (tl>0): vmcnt(17) [16 stores + 1 load after
// the needed load]; else vmcnt(1); last step vmcnt(0).
template <int L>
__global__ __launch_bounds__(512, 1)
void pgemm(const unsigned short* __restrict__ Aatom,
           const unsigned short* __restrict__ Agcl,
           const unsigned short* __restrict__ Wt,
           unsigned short* __restrict__ Pa,
           unsigned short* __restrict__ Pg)
{
  constexpr int RW = (L == 0) ? 512 : 256;
  const int ch = blockIdx.x, w = blockIdx.y;
  int side, f, nt;
  if (L == 0) { side = w >> 3; f = (w >> 1) & 3; nt = w & 1; }
  else        { side = w >> 2; f = w & 3; nt = 0; }
  int tbase, tcnt;
  if (L == 0) { tbase = (ch < 7) ? ch * 25 : 175 + (ch - 7) * 24; tcnt = (ch < 7) ? 25 : 24; }
  else        { tbase = (ch < 7) ? ch * 13 : 91 + (ch - 7) * 12;  tcnt = (ch < 7) ? 13 : 12; }

  const size_t wslot = (L == 0) ? ((size_t)side * 65536 + (size_t)(f * 2 + nt) * 8192)
                                : ((size_t)131072 + (size_t)side * 32768 + (size_t)f * 8192);
  const unsigned short* Wm = Wt + wslot * 8;
  const unsigned short* Ab = side ? (Agcl + (size_t)f * NAP2 * 256) : Aatom;
  unsigned short* P = (side ? Pg : Pa) + (size_t)f * NAP2 * RW + nt * 256;

  const int tid = threadIdx.x, lane = tid & 63, wid = tid >> 6;
  const int wm = wid >> 2, wn = wid & 3;     // 2x4 wave grid: 64 rows x 64 cols each
  const int hi = lane >> 4, lo = lane & 15;

  __shared__ unsigned short Wl[65536];       // 128 KB
  __shared__ unsigned short Ar[3][4096];     // 3 x 8 KB ring

  // stage W once
#pragma unroll
  for (int r = 0; r < 16; ++r)
    gld_lds16(Wm + ((size_t)(r * 8 + wid) * 64 + lane) * 8, &Wl[(r * 8 + wid) * 512]);

  const unsigned short* as = Ab + (size_t)tbase * 32768 + (size_t)(wid * 64 + lane) * 8;
  const int NS = tcnt * 8;

  f32x4 acc[4][4];
#pragma unroll
  for (int m = 0; m < 4; ++m)
#pragma unroll
    for (int n = 0; n < 4; ++n) acc[m][n] = (f32x4)0.f;

  // prologue: 2 A-steps in flight
  gld_lds16(as, &Ar[0][wid * 512]);
  gld_lds16(as + 4096, &Ar[1][wid * 512]);

  int cur = 0;                               // s % 3
  for (int tl = 0; tl < tcnt; ++tl) {
#pragma unroll
    for (int kb = 0; kb < 8; ++kb) {
      // counted wait for the load of this step's buffer
      if (kb == 1 || kb == 2) {
        if (tl > 0) asm volatile("s_waitcnt vmcnt(17)" ::: "memory");
        else        asm volatile("s_waitcnt vmcnt(1)" ::: "memory");
      } else if (kb == 7) {
        if (tl == tcnt - 1) asm volatile("s_waitcnt vmcnt(0)" ::: "memory");
        else                asm volatile("s_waitcnt vmcnt(1)" ::: "memory");
      } else {
        asm volatile("s_waitcnt vmcnt(1)" ::: "memory");
      }
      __builtin_amdgcn_sched_barrier(0);
      __builtin_amdgcn_s_barrier();
      __builtin_amdgcn_sched_barrier(0);

      // stage s+2
      {
        const int s = tl * 8 + kb;
        if (s + 2 < NS) {
          int b2 = cur + 2; if (b2 >= 3) b2 -= 3;
          gld_lds16(as + (size_t)(s + 2) * 4096, &Ar[b2][wid * 512]);
        }
      }

      // store previous tile AFTER the stage (keeps wait positions exact)
      if (kb == 0 && tl > 0) {
        const size_t rb = (size_t)(tbase + tl - 1) * 128 + wm * 64;
#pragma unroll
        for (int m = 0; m < 4; ++m)
#pragma unroll
          for (int n = 0; n < 4; ++n) {
            // swapped C/D: lane lo = output row (within 16), hi*4+r = output col
            union { unsigned short h[4]; uint2 u; } o;
#pragma unroll
            for (int r = 0; r < 4; ++r) { o.h[r] = f2bf(acc[m][n][r]); acc[m][n][r] = 0.f; }
            *(uint2*)&P[(rb + m * 16 + lo) * RW + wn * 64 + n * 16 + hi * 4] = o.u;
          }
      }

      const unsigned short* Abuf = Ar[cur];
      s16x8 bv[4], av[4];
#pragma unroll
      for (int n = 0; n < 4; ++n)
        bv[n] = *(const s16x8*)&Wl[(kb * 1024 + hi * 256 + wn * 64 + n * 16 + lo) * 8];
#pragma unroll
      for (int m = 0; m < 4; ++m)
        av[m] = *(const s16x8*)&Abuf[(hi * 128 + wm * 64 + m * 16 + lo) * 8];
      // swapped operands: D^T fragment -> lane holds 4 consecutive output cols
#pragma unroll
      for (int m = 0; m < 4; ++m)
#pragma unroll
        for (int n = 0; n < 4; ++n)
          acc[m][n] = __builtin_amdgcn_mfma_f32_16x16x32_bf16(bv[n], av[m], acc[m][n], 0, 0, 0);

      ++cur; if (cur >= 3) cur = 0;
    }
  }
  // final tile store
  {
    const size_t rb = (size_t)(tbase + tcnt - 1) * 128 + wm * 64;
#pragma unroll
    for (int m = 0; m < 4; ++m)
#pragma unroll
      for (int n = 0; n < 4; ++n) {
        union { unsigned short h[4]; uint2 u; } o;
#pragma unroll
        for (int r = 0; r < 4; ++r) o.h[r] = f2bf(acc[m][n][r]);
        *(uint2*)&P[(rb + m * 16 + lo) * RW + wn * 64 + n * 16 + hi * 4] = o.u;
      }
  }
}

// L0 message combine: one 32-lane group per clique, uint4 (16B) gathers.
__global__ __launch_bounds__(256)
void msg_combine(const unsigned short* __restrict__ Pa,
                 const unsigned short* __restrict__ Pg,
                 const int* __restrict__ gIdx,
                 const float* __restrict__ bM,
                 unsigned short* __restrict__ gclT1)
{
  const int grp = blockIdx.x * 8 + (threadIdx.x >> 5);    // < NF*NAP2
  const int cl = threadIdx.x & 31;
  const int f = grp / NAP2, g = grp - f * NAP2;
  const int tile = g >> 7, row = g & 127;
  const int kb = cl >> 2, c = cl & 3;
  unsigned short* dp = gclT1 + (size_t)f * NAP2 * 256 +
                       ((size_t)(tile * 8 + kb) * 512 + c * 128 + row) * 8;
  if (g >= NG) { *(uint4*)dp = make_uint4(0, 0, 0, 0); return; }
  const int cc = cl * 8;
  const int* ip = gIdx + (size_t)f * MM + g * 3;
  int i0 = ip[0], i1 = ip[1], i2 = ip[2];
  const unsigned short* PaF = Pa + (size_t)f * NAP2 * 512;
  union { unsigned short h[8]; uint4 u; } a0, a1, a2, pg, o;
  a0.u = *(const uint4*)(PaF + (size_t)i0 * 512 + cc);
  a1.u = *(const uint4*)(PaF + (size_t)i1 * 512 + cc);
  a2.u = *(const uint4*)(PaF + (size_t)i2 * 512 + cc);
  pg.u = *(const uint4*)(Pg + ((size_t)f * NAP2 + g) * 512 + cc);
  const float4 b0 = *(const float4*)(bM + f * 256 + cc);
  const float4 b1 = *(const float4*)(bM + f * 256 + cc + 4);
  const float bb[8] = {b0.x, b0.y, b0.z, b0.w, b1.x, b1.y, b1.z, b1.w};
#pragma unroll
  for (int j = 0; j < 8; ++j) {
    float m = fmaxf(fmaxf(bf2f(a0.h[j]), bf2f(a1.h[j])), bf2f(a2.h[j]));
    o.h[j] = f2bf(fmaxf(m + bf2f(pg.h[j]) + bb[j], 0.f));
  }
  *(uint4*)dp = o.u;
}

// Update combine: out[a] = max(0, max_occ(Pa[f][a] + Pg[f][g] + bU[f])).
// One wave per atom; 2 occurrences/step via half-waves; uint4 row reads.
template <int L>
__global__ __launch_bounds__(256)
void upd_combine(const unsigned short* __restrict__ Pa,
                 const unsigned short* __restrict__ Pg,
                 const uint32_t* __restrict__ offA,
                 const uint32_t* __restrict__ occList,
                 const float* __restrict__ bU,
                 unsigned short* __restrict__ outT,
                 float* __restrict__ outF)
{
  constexpr int RW = (L == 0) ? 512 : 256;
  constexpr int CO = (L == 0) ? 256 : 0;
  const int a = blockIdx.x * 4 + (threadIdx.x >> 6);
  const int lane = threadIdx.x & 63;
  const int h = lane >> 5, cl = lane & 31;
  const int cc = cl * 8;
  if (L == 0 && a >= NA) {
    if (a < NAP2 && h == 0) {
      int tile = a >> 7, row = a & 127;
      *(uint4*)(outT + ((size_t)(tile * 8 + (cl >> 2)) * 512 + (cl & 3) * 128 + row) * 8) =
          make_uint4(0, 0, 0, 0);
    }
    return;
  }
  if (a >= NA) return;

  float pa0[8], pa1[8], pa2[8], pa3[8];
  {
    union { unsigned short s[8]; uint4 u; } v;
#define LOADPA(F, DST)                                                          \
    v.u = *(const uint4*)(Pa + ((size_t)(F) * NAP2 + a) * RW + CO + cc);        \
    { const float4 b0 = *(const float4*)(bU + (F) * 256 + cc);                  \
      const float4 b1 = *(const float4*)(bU + (F) * 256 + cc + 4);              \
      DST[0]=bf2f(v.s[0])+b0.x; DST[1]=bf2f(v.s[1])+b0.y;                       \
      DST[2]=bf2f(v.s[2])+b0.z; DST[3]=bf2f(v.s[3])+b0.w;                       \
      DST[4]=bf2f(v.s[4])+b1.x; DST[5]=bf2f(v.s[5])+b1.y;                       \
      DST[6]=bf2f(v.s[6])+b1.z; DST[7]=bf2f(v.s[7])+b1.w; }
    LOADPA(0, pa0) LOADPA(1, pa1) LOADPA(2, pa2) LOADPA(3, pa3)
#undef LOADPA
  }

  float zm[8] = {0.f, 0.f, 0.f, 0.f, 0.f, 0.f, 0.f, 0.f};
  const uint32_t s = offA[a], e = offA[a + 1];
  for (uint32_t base = s; base < e; base += 64) {
    int cnt = (int)(e - base); if (cnt > 64) cnt = 64;
    uint32_t tmine = (base + lane < e) ? occList[base + lane] : 0u;
    for (int k = 0; k < cnt; k += 2) {
      int src = k + h;
      uint32_t t = __shfl(tmine, src);
      if (src < cnt) {
        int f = (int)(t / (uint32_t)MM);
        int g = (int)((t - (uint32_t)f * MM) / 3u);
        union { unsigned short s[8]; uint4 u; } v;
        v.u = *(const uint4*)(Pg + ((size_t)f * NAP2 + g) * RW + CO + cc);
#pragma unroll
        for (int j = 0; j < 8; ++j) {
          float paf = (f == 0) ? pa0[j] : (f == 1) ? pa1[j] : (f == 2) ? pa2[j] : pa3[j];
          zm[j] = fmaxf(zm[j], paf + bf2f(v.s[j]));
        }
      }
    }
  }
  // merge half-waves
#pragma unroll
  for (int j = 0; j < 8; ++j) zm[j] = fmaxf(zm[j], __shfl_xor(zm[j], 32));

  if (L == 0) {
    if (h == 0) {
      union { unsigned short s[8]; uint4 u; } o;
#pragma unroll
      for (int j = 0; j < 8; ++j) o.s[j] = f2bf(zm[j]);
      int tile = a >> 7, row = a & 127;
      *(uint4*)(outT + ((size_t)(tile * 8 + (cl >> 2)) * 512 + (cl & 3) * 128 + row) * 8) = o.u;
    }
  } else {
    float4 o;
    if (h == 0) { o.x = zm[0]; o.y = zm[1]; o.z = zm[2]; o.w = zm[3];
                  *(float4*)(outF + (size_t)a * 256 + cc) = o; }
    else        { o.x = zm[4]; o.y = zm[5]; o.z = zm[6]; o.w = zm[7];
                  *(float4*)(outF + (size_t)a * 256 + cc + 4) = o; }
  }
}

extern "C" void kernel_launch(void* const* d_in, const int* in_sizes, int n_in,
                              void* d_out, int out_size, void* d_ws, size_t ws_size,
                              hipStream_t stream) {
  const float* x  = (const float*)d_in[0];
  const int*   gi = (const int*)d_in[1];
  const float* fg = (const float*)d_in[2];
  const float* WM = (const float*)d_in[3];
  const float* bM = (const float*)d_in[4];
  const float* WU = (const float*)d_in[5];
  const float* bU = (const float*)d_in[6];
  float* out = (float*)d_out;

  char* ws = (char*)d_ws;
  size_t off_b = 0;
  auto alloc = [&](size_t b) { char* p = ws + off_b; off_b += (b + 255) & ~(size_t)255; return p; };
  unsigned short* atomT = (unsigned short*)alloc((size_t)NAP2 * 256 * 2);      // 25.6 MB
  unsigned short* gclT  = (unsigned short*)alloc((size_t)NF * NAP2 * 256 * 2); // 102.5 MB
  unsigned short* P0a   = (unsigned short*)alloc((size_t)NF * NAP2 * 512 * 2); // 205 MB
  unsigned short* P0g   = (unsigned short*)alloc((size_t)NF * NAP2 * 512 * 2); // 205 MB
  unsigned short* Wt    = (unsigned short*)alloc((size_t)196608 * 16);         // 3.15 MB
  uint32_t* cnt     = (uint32_t*)alloc((size_t)NA * 4);
  uint32_t* offA    = (uint32_t*)alloc((size_t)(NA + 1) * 4);
  uint32_t* bump    = (uint32_t*)alloc((size_t)NA * 4);
  uint32_t* occList = (uint32_t*)alloc((size_t)TOT * 4);

  unsigned short* P1a = P0a;
  unsigned short* P1g = P0a + (size_t)NF * NAP2 * 256;

  cvt_tile<<<NT2 * 16, 256, 0, stream>>>(x, atomT);
  cvt_tile<<<NF * NT2 * 16, 256, 0, stream>>>(fg, gclT);
  prep_w<<<768, 256, 0, stream>>>(WM, WU, Wt);
  hipMemsetAsync(cnt, 0, (size_t)NA * 4, stream);
  sort_count<<<(TOT + 255) / 256, 256, 0, stream>>>(gi, cnt);
  sort_scan<<<1, 1024, 0, stream>>>(cnt, offA, bump);
  sort_fill<<<(TOT + 255) / 256, 256, 0, stream>>>(gi, bump, occList);

  // layer 0
  pgemm<0><<<dim3(16, 16), 512, 0, stream>>>(atomT, gclT, Wt, P0a, P0g);
  msg_combine<<<NF * NAP2 / 8, 256, 0, stream>>>(P0a, P0g, gi, bM, gclT);        // gclT := gcl1
  upd_combine<0><<<NAP2 / 4, 256, 0, stream>>>(P0a, P0g, offA, occList, bU, atomT, nullptr);

  // layer 1
  pgemm<1><<<dim3(32, 8), 512, 0, stream>>>(atomT, gclT, Wt, P1a, P1g);
  upd_combine<1><<<(NA + 3) / 4, 256, 0, stream>>>(P1a, P1g, offA, occList, bU + 1024, nullptr, out);
}

// Round 9
// 914.879 us; speedup vs baseline: 2.0483x; 1.0992x over previous
//
#include <hip/hip_runtime.h>
#include <stdint.h>

#define NA 50000
#define DD 256
#define NF 4
#define NG 50000
#define MM 150000
#define TOT 600000
#define NAP2 50048        // 391 * 128
#define NT2 391
#define KK 256            // K per GEMM (split concat)

typedef __attribute__((ext_vector_type(8))) short s16x8;
typedef __attribute__((ext_vector_type(4))) float f32x4;

__device__ __forceinline__ unsigned short f2bf(float f) {
  union { float f; uint32_t u; } v; v.f = f;
  return (unsigned short)((v.u + 0x7FFFu + ((v.u >> 16) & 1u)) >> 16);  // RNE
}
__device__ __forceinline__ float bf2f(unsigned short h) {
  union { uint32_t u; float f; } v; v.u = ((uint32_t)h) << 16; return v.f;
}
__device__ __forceinline__ void gld_lds16(const void* g, void* l) {
  __builtin_amdgcn_global_load_lds(
      (const __attribute__((address_space(1))) uint32_t*)g,
      (__attribute__((address_space(3))) uint32_t*)l, 16, 0, 0);
}

// f32 [b][50000][256] -> tiled bf16 [b][tile=grow/128][kb][c][row=grow%128][8]
__global__ void cvt_tile(const float* __restrict__ src, unsigned short* __restrict__ dst) {
  int blk = blockIdx.x;                 // ((b*391 + tile)*8 + kb)*2 + cp
  int cp = blk & 1, kb = (blk >> 1) & 7, rem = blk >> 4;
  int tile = rem % NT2, b = rem / NT2;
  int cl = threadIdx.x >> 7, row = threadIdx.x & 127;
  int c = cp * 2 + cl;
  int grow = tile * 128 + row;
  union { unsigned short h[8]; uint4 u; } o;
  if (grow < NA) {
    const float* s = src + ((size_t)b * NA + grow) * 256 + kb * 32 + c * 8;
    float4 v0 = *(const float4*)s, v1 = *(const float4*)(s + 4);
    o.h[0]=f2bf(v0.x); o.h[1]=f2bf(v0.y); o.h[2]=f2bf(v0.z); o.h[3]=f2bf(v0.w);
    o.h[4]=f2bf(v1.x); o.h[5]=f2bf(v1.y); o.h[6]=f2bf(v1.z); o.h[7]=f2bf(v1.w);
  } else o.u = make_uint4(0, 0, 0, 0);
  *(uint4*)(dst + (size_t)b * NAP2 * 256 +
            ((size_t)(tile * 8 + kb) * 512 + c * 128 + row) * 8) = o.u;
}

// Weight pre-chunk: slot = [kb][c][n], value[e]=W[kb*32+c*8+e][n].
//   slots [0,65536): top0 [f][nt]; [65536,131072): bot0; [131072,163840): top1 [f];
//   [163840,196608): bot1 [f]
__global__ void prep_w(const float* __restrict__ WM, const float* __restrict__ WU,
                       unsigned short* __restrict__ Wt) {
  int t = blockIdx.x * 256 + threadIdx.x;
  if (t >= 196608) return;
  const float* src;
  if (t < 131072) {
    int e = t & 65535;
    int f = e >> 14, nt = (e >> 13) & 1, r = e & 8191;
    int k = ((r >> 10) << 5) + (((r >> 8) & 3) << 3) + ((t >> 16) << 8);
    int n = r & 255;
    src = (nt ? WU : WM) + ((size_t)f * 512 + k) * 256 + n;
  } else {
    int e = t - 131072;
    int bot = e >> 15;
    e &= 32767;
    int f = e >> 13, r = e & 8191;
    int k = ((r >> 10) << 5) + (((r >> 8) & 3) << 3) + (bot << 8);
    int n = r & 255;
    src = WU + ((size_t)(NF + f) * 512 + k) * 256 + n;
  }
  union { unsigned short h[8]; uint4 u; } o;
#pragma unroll
  for (int e2 = 0; e2 < 8; ++e2) o.h[e2] = f2bf(src[(size_t)e2 * 256]);
  ((uint4*)Wt)[t] = o.u;
}

// ---- counting-sort CSR of flat_idx ----
__global__ void sort_count(const int* __restrict__ gi, uint32_t* __restrict__ cnt) {
  int t = blockIdx.x * 256 + threadIdx.x;
  if (t < TOT) atomicAdd(&cnt[gi[t]], 1u);
}
__global__ void sort_scan(const uint32_t* __restrict__ cnt, uint32_t* __restrict__ off,
                          uint32_t* __restrict__ bump) {
  __shared__ uint32_t part[1024];
  const int t = threadIdx.x;
  const int CH = 49;
  int lo = t * CH, hi = lo + CH; if (hi > NA) hi = NA;
  uint32_t s = 0;
  for (int i = lo; i < hi; ++i) s += cnt[i];
  part[t] = s;
  __syncthreads();
  for (int d = 1; d < 1024; d <<= 1) {
    uint32_t v = (t >= d) ? part[t - d] : 0u;
    __syncthreads();
    part[t] += v;
    __syncthreads();
  }
  uint32_t run = (t == 0) ? 0u : part[t - 1];
  for (int i = lo; i < hi; ++i) { off[i] = run; bump[i] = run; run += cnt[i]; }
  if (t == 1023) off[NA] = part[1023];
}
__global__ void sort_fill(const int* __restrict__ gi, uint32_t* __restrict__ bump,
                          uint32_t* __restrict__ occList) {
  int t = blockIdx.x * 256 + threadIdx.x;
  if (t < TOT) { uint32_t r = atomicAdd(&bump[gi[t]], 1u); occList[r] = (uint32_t)t; }
}

// Persistent-W GEMM. W (128KB) in LDS; A streamed through a 4x8KB ring (3-phase
// lookahead). Stores of tile t-1 are spread 2/phase across tile t's 8 phases from
// an accS shadow copy, so the steady counted wait vmcnt(8) (=2 younger loads +
// 6 younger stores) never force-drains a store. Swapped-operand MFMA: lane holds
// 4 consecutive output cols -> uint2 stores.
template <int L>
__global__ __launch_bounds__(512, 2)
void pgemm(const unsigned short* __restrict__ Aatom,
           const unsigned short* __restrict__ Agcl,
           const unsigned short* __restrict__ Wt,
           unsigned short* __restrict__ Pa,
           unsigned short* __restrict__ Pg)
{
  constexpr int RW = (L == 0) ? 512 : 256;
  const int ch = blockIdx.x, w = blockIdx.y;
  int side, f, nt;
  if (L == 0) { side = w >> 3; f = (w >> 1) & 3; nt = w & 1; }
  else        { side = w >> 2; f = w & 3; nt = 0; }
  int tbase, tcnt;
  if (L == 0) { tbase = (ch < 7) ? ch * 25 : 175 + (ch - 7) * 24; tcnt = (ch < 7) ? 25 : 24; }
  else        { tbase = (ch < 7) ? ch * 13 : 91 + (ch - 7) * 12;  tcnt = (ch < 7) ? 13 : 12; }

  const size_t wslot = (L == 0) ? ((size_t)side * 65536 + (size_t)(f * 2 + nt) * 8192)
                                : ((size_t)131072 + (size_t)side * 32768 + (size_t)f * 8192);
  const unsigned short* Wm = Wt + wslot * 8;
  const unsigned short* Ab = side ? (Agcl + (size_t)f * NAP2 * 256) : Aatom;
  unsigned short* P = (side ? Pg : Pa) + (size_t)f * NAP2 * RW + nt * 256;

  const int tid = threadIdx.x, lane = tid & 63, wid = tid >> 6;
  const int wm = wid >> 2, wn = wid & 3;     // 2x4 wave grid: 64 rows x 64 cols each
  const int hi = lane >> 4, lo = lane & 15;

  __shared__ unsigned short Wl[65536];       // 128 KB
  __shared__ unsigned short Ar[4][4096];     // 4 x 8 KB ring (160 KB total = HW max)

  // stage W once
#pragma unroll
  for (int r = 0; r < 16; ++r)
    gld_lds16(Wm + ((size_t)(r * 8 + wid) * 64 + lane) * 8, &Wl[(r * 8 + wid) * 512]);

  const unsigned short* as = Ab + (size_t)tbase * 32768 + (size_t)(wid * 64 + lane) * 8;
  const int NS = tcnt * 8;

  f32x4 acc[4][4], accS[4][4];
#pragma unroll
  for (int m = 0; m < 4; ++m)
#pragma unroll
    for (int n = 0; n < 4; ++n) acc[m][n] = (f32x4)0.f;

  // prologue: 3 A-steps in flight
  gld_lds16(as, &Ar[0][wid * 512]);
  gld_lds16(as + 4096, &Ar[1][wid * 512]);
  gld_lds16(as + 8192, &Ar[2][wid * 512]);

  // MFMA+LDS-read body for step s (buffer s&3), compile-time kb
#define MFMA_BODY(KB, S)                                                        \
  {                                                                             \
    const unsigned short* Abuf = Ar[(S) & 3];                                   \
    s16x8 bv[4], av[4];                                                         \
    _Pragma("unroll")                                                           \
    for (int n = 0; n < 4; ++n)                                                 \
      bv[n] = *(const s16x8*)&Wl[((KB) * 1024 + hi * 256 + wn * 64 + n * 16 + lo) * 8]; \
    _Pragma("unroll")                                                           \
    for (int m = 0; m < 4; ++m)                                                 \
      av[m] = *(const s16x8*)&Abuf[(hi * 128 + wm * 64 + m * 16 + lo) * 8];     \
    _Pragma("unroll")                                                           \
    for (int m = 0; m < 4; ++m)                                                 \
      _Pragma("unroll")                                                         \
      for (int n = 0; n < 4; ++n)                                               \
        acc[m][n] = __builtin_amdgcn_mfma_f32_16x16x32_bf16(bv[n], av[m], acc[m][n], 0, 0, 0); \
  }

#define WAITB(VM)                                                               \
  asm volatile("s_waitcnt vmcnt(" #VM ")" ::: "memory");                        \
  __builtin_amdgcn_sched_barrier(0);                                            \
  __builtin_amdgcn_s_barrier();                                                 \
  __builtin_amdgcn_sched_barrier(0);

  // ---- tile 0: no stores ----
#pragma unroll
  for (int kb = 0; kb < 8; ++kb) {
    WAITB(2)
    gld_lds16(as + (size_t)(kb + 3) * 4096, &Ar[(kb + 3) & 3][wid * 512]);
    __builtin_amdgcn_sched_barrier(0);
    MFMA_BODY(kb, kb)
  }
#pragma unroll
  for (int m = 0; m < 4; ++m)
#pragma unroll
    for (int n = 0; n < 4; ++n) { accS[m][n] = acc[m][n]; acc[m][n] = (f32x4)0.f; }

  // ---- tiles 1..tcnt-1: 2 stores/phase from accS ----
  for (int tl = 1; tl < tcnt; ++tl) {
    const size_t rbPrev = (size_t)(tbase + tl - 1) * 128 + wm * 64;
#pragma unroll
    for (int kb = 0; kb < 8; ++kb) {
      const int s = tl * 8 + kb;
      // counted waits derived from in-order vmcnt queue positions
      if (kb == 0)      { if (tl == 1) { WAITB(2) } else { WAITB(8) } }
      else if (kb == 1) { if (tl == 1) { WAITB(4) } else { WAITB(8) } }
      else if (kb == 2) { if (tl == 1) { WAITB(6) } else { WAITB(8) } }
      else if (kb == 6) { if (tl == tcnt - 1) { WAITB(7) } else { WAITB(8) } }
      else if (kb == 7) { if (tl == tcnt - 1) { WAITB(6) } else { WAITB(8) } }
      else              { WAITB(8) }

      if (s + 3 < NS)
        gld_lds16(as + (size_t)(s + 3) * 4096, &Ar[(s + 3) & 3][wid * 512]);
      __builtin_amdgcn_sched_barrier(0);

      // 2 stores of the previous tile's accS
#pragma unroll
      for (int j = 0; j < 2; ++j) {
        const int p = kb * 2 + j, m = p >> 2, n = p & 3;
        union { unsigned short h[4]; uint2 u; } o;
#pragma unroll
        for (int r = 0; r < 4; ++r) o.h[r] = f2bf(accS[m][n][r]);
        *(uint2*)&P[(rbPrev + m * 16 + lo) * RW + wn * 64 + n * 16 + hi * 4] = o.u;
      }

      MFMA_BODY(kb, s)
    }
    if (tl < tcnt - 1) {
#pragma unroll
      for (int m = 0; m < 4; ++m)
#pragma unroll
        for (int n = 0; n < 4; ++n) { accS[m][n] = acc[m][n]; acc[m][n] = (f32x4)0.f; }
    }
  }

  // ---- final tile store (from acc; no waits needed) ----
  {
    const size_t rb = (size_t)(tbase + tcnt - 1) * 128 + wm * 64;
#pragma unroll
    for (int m = 0; m < 4; ++m)
#pragma unroll
      for (int n = 0; n < 4; ++n) {
        union { unsigned short h[4]; uint2 u; } o;
#pragma unroll
        for (int r = 0; r < 4; ++r) o.h[r] = f2bf(acc[m][n][r]);
        *(uint2*)&P[(rb + m * 16 + lo) * RW + wn * 64 + n * 16 + hi * 4] = o.u;
      }
  }
#undef MFMA_BODY
#undef WAITB
}

// L0 message combine: one 32-lane group per clique, uint4 (16B) gathers.
__global__ __launch_bounds__(256)
void msg_combine(const unsigned short* __restrict__ Pa,
                 const unsigned short* __restrict__ Pg,
                 const int* __restrict__ gIdx,
                 const float* __restrict__ bM,
                 unsigned short* __restrict__ gclT1)
{
  const int grp = blockIdx.x * 8 + (threadIdx.x >> 5);    // < NF*NAP2
  const int cl = threadIdx.x & 31;
  const int f = grp / NAP2, g = grp - f * NAP2;
  const int tile = g >> 7, row = g & 127;
  const int kb = cl >> 2, c = cl & 3;
  unsigned short* dp = gclT1 + (size_t)f * NAP2 * 256 +
                       ((size_t)(tile * 8 + kb) * 512 + c * 128 + row) * 8;
  if (g >= NG) { *(uint4*)dp = make_uint4(0, 0, 0, 0); return; }
  const int cc = cl * 8;
  const int* ip = gIdx + (size_t)f * MM + g * 3;
  int i0 = ip[0], i1 = ip[1], i2 = ip[2];
  const unsigned short* PaF = Pa + (size_t)f * NAP2 * 512;
  union { unsigned short h[8]; uint4 u; } a0, a1, a2, pg, o;
  a0.u = *(const uint4*)(PaF + (size_t)i0 * 512 + cc);
  a1.u = *(const uint4*)(PaF + (size_t)i1 * 512 + cc);
  a2.u = *(const uint4*)(PaF + (size_t)i2 * 512 + cc);
  pg.u = *(const uint4*)(Pg + ((size_t)f * NAP2 + g) * 512 + cc);
  const float4 b0 = *(const float4*)(bM + f * 256 + cc);
  const float4 b1 = *(const float4*)(bM + f * 256 + cc + 4);
  const float bb[8] = {b0.x, b0.y, b0.z, b0.w, b1.x, b1.y, b1.z, b1.w};
#pragma unroll
  for (int j = 0; j < 8; ++j) {
    float m = fmaxf(fmaxf(bf2f(a0.h[j]), bf2f(a1.h[j])), bf2f(a2.h[j]));
    o.h[j] = f2bf(fmaxf(m + bf2f(pg.h[j]) + bb[j], 0.f));
  }
  *(uint4*)dp = o.u;
}

// Update combine: out[a] = max(0, max_occ(Pa[f][a] + Pg[f][g] + bU[f])).
// One wave per atom; 2 occurrences/step via half-waves; uint4 row reads.
template <int L>
__global__ __launch_bounds__(256)
void upd_combine(const unsigned short* __restrict__ Pa,
                 const unsigned short* __restrict__ Pg,
                 const uint32_t* __restrict__ offA,
                 const uint32_t* __restrict__ occList,
                 const float* __restrict__ bU,
                 unsigned short* __restrict__ outT,
                 float* __restrict__ outF)
{
  constexpr int RW = (L == 0) ? 512 : 256;
  constexpr int CO = (L == 0) ? 256 : 0;
  const int a = blockIdx.x * 4 + (threadIdx.x >> 6);
  const int lane = threadIdx.x & 63;
  const int h = lane >> 5, cl = lane & 31;
  const int cc = cl * 8;
  if (L == 0 && a >= NA) {
    if (a < NAP2 && h == 0) {
      int tile = a >> 7, row = a & 127;
      *(uint4*)(outT + ((size_t)(tile * 8 + (cl >> 2)) * 512 + (cl & 3) * 128 + row) * 8) =
          make_uint4(0, 0, 0, 0);
    }
    return;
  }
  if (a >= NA) return;

  float pa0[8], pa1[8], pa2[8], pa3[8];
  {
    union { unsigned short s[8]; uint4 u; } v;
#define LOADPA(F, DST)                                                          \
    v.u = *(const uint4*)(Pa + ((size_t)(F) * NAP2 + a) * RW + CO + cc);        \
    { const float4 b0 = *(const float4*)(bU + (F) * 256 + cc);                  \
      const float4 b1 = *(const float4*)(bU + (F) * 256 + cc + 4);              \
      DST[0]=bf2f(v.s[0])+b0.x; DST[1]=bf2f(v.s[1])+b0.y;                       \
      DST[2]=bf2f(v.s[2])+b0.z; DST[3]=bf2f(v.s[3])+b0.w;                       \
      DST[4]=bf2f(v.s[4])+b1.x; DST[5]=bf2f(v.s[5])+b1.y;                       \
      DST[6]=bf2f(v.s[6])+b1.z; DST[7]=bf2f(v.s[7])+b1.w; }
    LOADPA(0, pa0) LOADPA(1, pa1) LOADPA(2, pa2) LOADPA(3, pa3)
#undef LOADPA
  }

  float zm[8] = {0.f, 0.f, 0.f, 0.f, 0.f, 0.f, 0.f, 0.f};
  const uint32_t s = offA[a], e = offA[a + 1];
  for (uint32_t base = s; base < e; base += 64) {
    int cnt = (int)(e - base); if (cnt > 64) cnt = 64;
    uint32_t tmine = (base + lane < e) ? occList[base + lane] : 0u;
    for (int k = 0; k < cnt; k += 2) {
      int src = k + h;
      uint32_t t = __shfl(tmine, src);
      if (src < cnt) {
        int f = (int)(t / (uint32_t)MM);
        int g = (int)((t - (uint32_t)f * MM) / 3u);
        union { unsigned short s[8]; uint4 u; } v;
        v.u = *(const uint4*)(Pg + ((size_t)f * NAP2 + g) * RW + CO + cc);
#pragma unroll
        for (int j = 0; j < 8; ++j) {
          float paf = (f == 0) ? pa0[j] : (f == 1) ? pa1[j] : (f == 2) ? pa2[j] : pa3[j];
          zm[j] = fmaxf(zm[j], paf + bf2f(v.s[j]));
        }
      }
    }
  }
  // merge half-waves
#pragma unroll
  for (int j = 0; j < 8; ++j) zm[j] = fmaxf(zm[j], __shfl_xor(zm[j], 32));

  if (L == 0) {
    if (h == 0) {
      union { unsigned short s[8]; uint4 u; } o;
#pragma unroll
      for (int j = 0; j < 8; ++j) o.s[j] = f2bf(zm[j]);
      int tile = a >> 7, row = a & 127;
      *(uint4*)(outT + ((size_t)(tile * 8 + (cl >> 2)) * 512 + (cl & 3) * 128 + row) * 8) = o.u;
    }
  } else {
    float4 o;
    if (h == 0) { o.x = zm[0]; o.y = zm[1]; o.z = zm[2]; o.w = zm[3];
                  *(float4*)(outF + (size_t)a * 256 + cc) = o; }
    else        { o.x = zm[4]; o.y = zm[5]; o.z = zm[6]; o.w = zm[7];
                  *(float4*)(outF + (size_t)a * 256 + cc + 4) = o; }
  }
}

extern "C" void kernel_launch(void* const* d_in, const int* in_sizes, int n_in,
                              void* d_out, int out_size, void* d_ws, size_t ws_size,
                              hipStream_t stream) {
  const float* x  = (const float*)d_in[0];
  const int*   gi = (const int*)d_in[1];
  const float* fg = (const float*)d_in[2];
  const float* WM = (const float*)d_in[3];
  const float* bM = (const float*)d_in[4];
  const float* WU = (const float*)d_in[5];
  const float* bU = (const float*)d_in[6];
  float* out = (float*)d_out;

  char* ws = (char*)d_ws;
  size_t off_b = 0;
  auto alloc = [&](size_t b) { char* p = ws + off_b; off_b += (b + 255) & ~(size_t)255; return p; };
  unsigned short* atomT = (unsigned short*)alloc((size_t)NAP2 * 256 * 2);      // 25.6 MB
  unsigned short* gclT  = (unsigned short*)alloc((size_t)NF * NAP2 * 256 * 2); // 102.5 MB
  unsigned short* P0a   = (unsigned short*)alloc((size_t)NF * NAP2 * 512 * 2); // 205 MB
  unsigned short* P0g   = (unsigned short*)alloc((size_t)NF * NAP2 * 512 * 2); // 205 MB
  unsigned short* Wt    = (unsigned short*)alloc((size_t)196608 * 16);         // 3.15 MB
  uint32_t* cnt     = (uint32_t*)alloc((size_t)NA * 4);
  uint32_t* offA    = (uint32_t*)alloc((size_t)(NA + 1) * 4);
  uint32_t* bump    = (uint32_t*)alloc((size_t)NA * 4);
  uint32_t* occList = (uint32_t*)alloc((size_t)TOT * 4);

  unsigned short* P1a = P0a;
  unsigned short* P1g = P0a + (size_t)NF * NAP2 * 256;

  cvt_tile<<<NT2 * 16, 256, 0, stream>>>(x, atomT);
  cvt_tile<<<NF * NT2 * 16, 256, 0, stream>>>(fg, gclT);
  prep_w<<<768, 256, 0, stream>>>(WM, WU, Wt);
  hipMemsetAsync(cnt, 0, (size_t)NA * 4, stream);
  sort_count<<<(TOT + 255) / 256, 256, 0, stream>>>(gi, cnt);
  sort_scan<<<1, 1024, 0, stream>>>(cnt, offA, bump);
  sort_fill<<<(TOT + 255) / 256, 256, 0, stream>>>(gi, bump, occList);

  // layer 0
  pgemm<0><<<dim3(16, 16), 512, 0, stream>>>(atomT, gclT, Wt, P0a, P0g);
  msg_combine<<<NF * NAP2 / 8, 256, 0, stream>>>(P0a, P0g, gi, bM, gclT);        // gclT := gcl1
  upd_combine<0><<<NAP2 / 4, 256, 0, stream>>>(P0a, P0g, offA, occList, bU, atomT, nullptr);

  // layer 1
  pgemm<1><<<dim3(32, 8), 512, 0, stream>>>(atomT, gclT, Wt, P1a, P1g);
  upd_combine<1><<<(NA + 3) / 4, 256, 0, stream>>>(P1a, P1g, offA, occList, bU + 1024, nullptr, out);
}